// Round 7
// baseline (683.060 us; speedup 1.0000x reference)
//
#include <hip/hip_runtime.h>
#include <math.h>

// ---------------- problem constants ----------------
#define D     256
#define NH    8
#define HDIM  32
#define NL    4
#define NPT   4
#define DFF   1024
#define BB    2
#define LT    20
#define LQ    20197
#define NROWS (BB*LQ)                 // 40394
#define SFL   ((size_t)NROWS * D)     // floats per N x 256 buffer

typedef __attribute__((ext_vector_type(8))) short bf16x8;
typedef __attribute__((ext_vector_type(4))) float f32x4;
typedef __attribute__((ext_vector_type(2))) float f32x2;

__device__ __forceinline__ unsigned short f2b(float f) {
    unsigned int u = __float_as_uint(f);
    unsigned int r = (u + 0x7FFFu + ((u >> 16) & 1u)) >> 16;   // RNE
    return (unsigned short)r;
}
__device__ __forceinline__ float b2f(unsigned short u) {
    return __uint_as_float((unsigned int)u << 16);
}
__device__ __forceinline__ unsigned int pk2(float a, float b) {
    return (unsigned int)f2b(a) | ((unsigned int)f2b(b) << 16);
}

// DPP quad_perm helpers (compile-time control). Broadcast-from-quad-lane-L
// control word is L*0b01010101 = L*85. xor1 = 0xB1, xor2 = 0x4E.
template<int CTRL>
__device__ __forceinline__ int dppi(int v) {
    return __builtin_amdgcn_update_dpp(0, v, CTRL, 0xF, 0xF, true);
}
template<int CTRL>
__device__ __forceinline__ float dppf(float v) {
    return __uint_as_float((unsigned int)__builtin_amdgcn_update_dpp(
        0, (int)__float_as_uint(v), CTRL, 0xF, 0xF, true));
}

#define GLDS16(g, l) __builtin_amdgcn_global_load_lds( \
    (const __attribute__((address_space(1))) unsigned int*)(g), \
    (__attribute__((address_space(3))) unsigned int*)(l), 16, 0, 0)

// =====================================================================
// bf16 MFMA GEMM (128x128 tile): used only where grid is already large
// (step 12: N=1024 -> 2528 blocks). 4 waves (2x2 of 64x64), dbuf.
// =====================================================================
__global__ __launch_bounds__(256) void gemm_mfma(const unsigned short* __restrict__ A,
                                                 const unsigned short* __restrict__ W,
                                                 const float* __restrict__ bias,
                                                 float* __restrict__ Cf,
                                                 unsigned short* __restrict__ Cb,
                                                 int M, int Nout, int K, int relu)
{
    __shared__ __align__(16) unsigned short As[2][128 * 32];   // 2 x 8 KB
    __shared__ __align__(16) unsigned short Ws[2][128 * 32];   // 2 x 8 KB
    const int tid  = threadIdx.x;
    const int wave = tid >> 6, lane = tid & 63;
    const int row0 = blockIdx.x * 128, n0 = blockIdx.y * 128;
    const int wm = (wave >> 1) * 64, wn = (wave & 1) * 64;

    const int srow = (wave << 5) + (lane >> 2);
    const int kcol = (lane & 3) << 3;
    const int ar0 = min(row0 + srow,      M - 1);
    const int ar1 = min(row0 + srow + 16, M - 1);
    const unsigned short* Ap0 = A + (size_t)ar0 * K + kcol;
    const unsigned short* Ap1 = A + (size_t)ar1 * K + kcol;
    const unsigned short* Wp0 = W + (size_t)(n0 + srow) * K + kcol;
    const unsigned short* Wp1 = W + (size_t)(n0 + srow + 16) * K + kcol;
    const int aoff0 = (wave << 10);          // per-wave staging offset (shorts)
    const int aoff1 = (wave << 10) + 512;

    f32x4 acc[4][4];
#pragma unroll
    for (int i = 0; i < 4; ++i)
#pragma unroll
        for (int j = 0; j < 4; ++j)
#pragma unroll
            for (int r = 0; r < 4; ++r) acc[i][j][r] = 0.f;

    const int fr = lane & 15;
    const int fk = (lane >> 4) << 3;

    // prologue: stage tile 0 into buffer 0
    GLDS16(Ap0, &As[0][aoff0]);
    GLDS16(Ap1, &As[0][aoff1]);
    GLDS16(Wp0, &Ws[0][aoff0]);
    GLDS16(Wp1, &Ws[0][aoff1]);
    __syncthreads();

    const int nt = K >> 5;
    int cur = 0;
    for (int t = 0; t < nt; ++t) {
        if (t + 1 < nt) {
            const int k1 = (t + 1) << 5;
            GLDS16(Ap0 + k1, &As[cur ^ 1][aoff0]);
            GLDS16(Ap1 + k1, &As[cur ^ 1][aoff1]);
            GLDS16(Wp0 + k1, &Ws[cur ^ 1][aoff0]);
            GLDS16(Wp1 + k1, &Ws[cur ^ 1][aoff1]);
        }
        bf16x8 af[4], wf[4];
#pragma unroll
        for (int t4 = 0; t4 < 4; ++t4) {
            af[t4] = *(const bf16x8*)&As[cur][(wm + t4 * 16 + fr) * 32 + fk];
            wf[t4] = *(const bf16x8*)&Ws[cur][(wn + t4 * 16 + fr) * 32 + fk];
        }
#pragma unroll
        for (int i = 0; i < 4; ++i)
#pragma unroll
            for (int j = 0; j < 4; ++j)
                acc[i][j] = __builtin_amdgcn_mfma_f32_16x16x32_bf16(af[i], wf[j], acc[i][j], 0, 0, 0);
        __syncthreads();
        cur ^= 1;
    }

    const int rq = (lane >> 4) << 2;
    const int cq = lane & 15;
#pragma unroll
    for (int mt = 0; mt < 4; ++mt) {
#pragma unroll
        for (int r = 0; r < 4; ++r) {
            const int row = row0 + wm + mt * 16 + rq + r;
            if (row < M) {
#pragma unroll
                for (int nt2 = 0; nt2 < 4; ++nt2) {
                    const int c = n0 + wn + nt2 * 16 + cq;
                    float v = acc[mt][nt2][r] + bias[c];
                    if (relu) v = fmaxf(v, 0.f);
                    if (Cb) Cb[(size_t)row * Nout + c] = f2b(v);
                    else    Cf[(size_t)row * Nout + c] = v;
                }
            }
        }
    }
}

// =====================================================================
// bf16 MFMA GEMM, 64x128 tile — thin GEMMs (r5: grid-starvation fix, -32us).
// v2 (r6): BK=64 effective — stage TWO BK=32 sub-tiles (separate LDS
// sub-buffers, identical proven [row][32] addressing) before ONE barrier
// pair. Halves barrier count (K=256: 16->8; K=1024: 64->32); every barrier
// was a full vmcnt-drain exposure point for all 4 waves. LDS 12->24 KB
// (still >=5 blocks/CU). K%64==0 required (K=256/1024 here).
// =====================================================================
__global__ __launch_bounds__(256) void gemm_mfma64(const unsigned short* __restrict__ A,
                                                   const unsigned short* __restrict__ W,
                                                   const float* __restrict__ bias,
                                                   float* __restrict__ Cf,
                                                   unsigned short* __restrict__ Cb,
                                                   int M, int Nout, int K, int relu)
{
    __shared__ __align__(16) unsigned short As[2][64 * 32];     // 2 x 4 KB
    __shared__ __align__(16) unsigned short Ws[2][128 * 32];    // 2 x 8 KB
    const int tid  = threadIdx.x;
    const int wave = tid >> 6, lane = tid & 63;
    const int row0 = blockIdx.x * 64, n0 = blockIdx.y * 128;
    const int wn = wave << 5;                 // col offset 0/32/64/96

    // staging: wave v stages A rows [16v,16v+16) and W rows [32v,32v+32)
    const int srow = lane >> 2;
    const int kcol = (lane & 3) << 3;
    const int arow = min(row0 + (wave << 4) + srow, M - 1);
    const unsigned short* Ap  = A + (size_t)arow * K + kcol;
    const unsigned short* Wp0 = W + (size_t)(n0 + (wave << 5) + srow) * K + kcol;
    const unsigned short* Wp1 = W + (size_t)(n0 + (wave << 5) + 16 + srow) * K + kcol;
    const int aoff  = wave << 9;              // 16 rows * 32 = 512 shorts/wave
    const int woff0 = wave << 10;             // 32 rows * 32 = 1024 shorts/wave
    const int woff1 = (wave << 10) + 512;

    f32x4 acc[4][2];
#pragma unroll
    for (int i = 0; i < 4; ++i)
#pragma unroll
        for (int j = 0; j < 2; ++j)
#pragma unroll
            for (int r = 0; r < 4; ++r) acc[i][j][r] = 0.f;

    const int fr = lane & 15;
    const int fk = (lane >> 4) << 3;

    for (int k0 = 0; k0 < K; k0 += 64) {
        // stage both k-halves of this 64-wide step before one barrier
        GLDS16(Ap + k0,       &As[0][aoff]);
        GLDS16(Wp0 + k0,      &Ws[0][woff0]);
        GLDS16(Wp1 + k0,      &Ws[0][woff1]);
        GLDS16(Ap + k0 + 32,  &As[1][aoff]);
        GLDS16(Wp0 + k0 + 32, &Ws[1][woff0]);
        GLDS16(Wp1 + k0 + 32, &Ws[1][woff1]);
        __syncthreads();
#pragma unroll
        for (int half = 0; half < 2; ++half) {
            bf16x8 af[4], wf[2];
#pragma unroll
            for (int i = 0; i < 4; ++i)
                af[i] = *(const bf16x8*)&As[half][(i * 16 + fr) * 32 + fk];
#pragma unroll
            for (int j = 0; j < 2; ++j)
                wf[j] = *(const bf16x8*)&Ws[half][(wn + j * 16 + fr) * 32 + fk];
#pragma unroll
            for (int i = 0; i < 4; ++i)
#pragma unroll
                for (int j = 0; j < 2; ++j)
                    acc[i][j] = __builtin_amdgcn_mfma_f32_16x16x32_bf16(af[i], wf[j], acc[i][j], 0, 0, 0);
        }
        __syncthreads();
    }

    const int rq = (lane >> 4) << 2;
    const int cq = lane & 15;
#pragma unroll
    for (int i = 0; i < 4; ++i) {
#pragma unroll
        for (int r = 0; r < 4; ++r) {
            const int row = row0 + i * 16 + rq + r;
            if (row < M) {
#pragma unroll
                for (int j = 0; j < 2; ++j) {
                    const int c = n0 + wn + j * 16 + cq;
                    float v = acc[i][j][r] + bias[c];
                    if (relu) v = fmaxf(v, 0.f);
                    if (Cb) Cb[(size_t)row * Nout + c] = f2b(v);
                    else    Cf[(size_t)row * Nout + c] = v;
                }
            }
        }
    }
}

// ---------------------------------------------------------------------
// batched fp32 -> bf16 weight cast (8 segments)
// ---------------------------------------------------------------------
struct W8 {
    const float* s[8];
    unsigned short* d[8];
    int n[8];
};
__global__ __launch_bounds__(256) void cast_w8(W8 w)
{
    const int seg = blockIdx.y;
    const int n = w.n[seg];
    const float* s = w.s[seg];
    unsigned short* d = w.d[seg];
    for (int i = blockIdx.x * 256 + threadIdx.x; i < n; i += gridDim.x * 256)
        d[i] = f2b(s[i]);
}

// concat so_b(256) + aw_b(128) -> o(384)
__global__ __launch_bounds__(384) void cat_bias(const float* __restrict__ sb,
                                                const float* __restrict__ ab,
                                                float* __restrict__ o)
{
    const int t = threadIdx.x;
    o[t] = (t < 256) ? sb[t] : ab[t - 256];
}

// srcb = bf16(src); qbf = bf16(src + pos)    (one pass)
__global__ __launch_bounds__(256) void cast_pair(const float4* __restrict__ src,
                                                 const float4* __restrict__ pos,
                                                 ushort4* __restrict__ srcb,
                                                 ushort4* __restrict__ qbf, int n4)
{
    const int i = blockIdx.x * 256 + threadIdx.x;
    if (i < n4) {
        const float4 s = src[i], p = pos[i];
        srcb[i] = make_ushort4(f2b(s.x), f2b(s.y), f2b(s.z), f2b(s.w));
        qbf[i]  = make_ushort4(f2b(s.x + p.x), f2b(s.y + p.y), f2b(s.z + p.z), f2b(s.w + p.w));
    }
}

// ---------------------------------------------------------------------
// multi-scale deformable sampling v7 (r6 fix: macro-hygiene rename of
// GATHER temps gw_/gp_, no design change).
// v6 structure (distributed coord math + level-major gather, 92 us) with
// PACKED-f32 accumulation: acc as 4x float2, gather fmas via
// __builtin_elementwise_fma on <2 x float> -> v_pk_fma_f32 (full-rate on
// gfx90a+). Per gather: 8 unpack + 4 pk_fma (~12 VALU) vs 16 before.
// ---------------------------------------------------------------------
#define SEL4(a0,a1,a2,a3) (j < 2 ? (j == 0 ? (a0) : (a1)) : (j == 2 ? (a2) : (a3)))

__global__ __launch_bounds__(256) void msdeform(const unsigned short* __restrict__ value,
                                                const float* __restrict__ oa,
                                                const float* __restrict__ refp,
                                                unsigned short* __restrict__ out)
{
    const int tid  = threadIdx.x;
    const int lane = tid & 63;
    const int row  = blockIdx.x * 8 + ((tid >> 6) << 1) + (lane >> 5);
    if (row >= NROWS) return;
    const int b   = row / LQ;
    const int sub = lane & 31;
    const int h   = sub >> 2;
    const int j   = sub & 3;                 // this lane's level AND channel-chunk
    const int ch  = (h << 5) + (j << 3);
    const unsigned short* vbase = value + (size_t)b * LQ * D + ch;

    const float* orow = oa + (size_t)row * 384;
    const float4 o0 = *(const float4*)(orow + (h << 5) + (j << 3));
    const float4 o1 = *(const float4*)(orow + (h << 5) + (j << 3) + 4);
    const float oxr[4] = {o0.x, o0.z, o1.x, o1.z};
    const float oyr[4] = {o0.y, o0.w, o1.y, o1.w};
    const float4 lg = *(const float4*)(orow + 256 + (h << 4) + (j << 2));
    float mx = fmaxf(fmaxf(lg.x, lg.y), fmaxf(lg.z, lg.w));
    mx = fmaxf(mx, dppf<0xB1>(mx));
    mx = fmaxf(mx, dppf<0x4E>(mx));
    const float e0 = __expf(lg.x - mx), e1 = __expf(lg.y - mx);
    const float e2 = __expf(lg.z - mx), e3 = __expf(lg.w - mx);
    float sm = e0 + e1 + e2 + e3;
    sm += dppf<0xB1>(sm);
    sm += dppf<0x4E>(sm);
    const float inv = 1.f / sm;
    const float pr[4] = {e0 * inv, e1 * inv, e2 * inv, e3 * inv};

    const int   Wi   = SEL4(152, 76, 38, 19);
    const int   Hi   = SEL4(100, 50, 25, 13);
    const int   st   = SEL4(0, 15200, 19000, 19950);
    const float invW = SEL4(1.f/152.f, 1.f/76.f, 1.f/38.f, 1.f/19.f);
    const float invH = SEL4(1.f/100.f, 1.f/50.f, 1.f/25.f, 1.f/13.f);
    const float Wf = (float)Wi, Hf = (float)Hi;
    const float2 rxy = *(const float2*)(refp + (size_t)row * 8 + (j << 1));

    unsigned int ip[8];
    float wcs[16];
#pragma unroll
    for (int p = 0; p < 4; ++p) {
        const float x = fmaf(oxr[p], invW, rxy.x) * Wf - 0.5f;
        const float y = fmaf(oyr[p], invH, rxy.y) * Hf - 0.5f;
        const float x0f = floorf(x), y0f = floorf(y);
        const float lx = x - x0f, ly = y - y0f;
        const int x0 = (int)x0f, y0 = (int)y0f;
        const int x1 = x0 + 1,  y1 = y0 + 1;
        const float vx0 = (x0 >= 0 && x0 < Wi) ? 1.f : 0.f;
        const float vx1 = (x1 >= 0 && x1 < Wi) ? 1.f : 0.f;
        const float vy0 = (y0 >= 0 && y0 < Hi) ? 1.f : 0.f;
        const float vy1 = (y1 >= 0 && y1 < Hi) ? 1.f : 0.f;
        const int cx0 = min(max(x0, 0), Wi - 1), cx1 = min(max(x1, 0), Wi - 1);
        const int cy0 = min(max(y0, 0), Hi - 1), cy1 = min(max(y1, 0), Hi - 1);
        const float wap = pr[p];
        const float wx0 = (1.f - lx) * vx0,        wx1 = lx * vx1;
        const float wy0 = (1.f - ly) * vy0 * wap,  wy1 = ly * vy1 * wap;
        const int r0 = st + cy0 * Wi, r1 = st + cy1 * Wi;
        ip[2*p]     = (unsigned int)(r0 + cx0) | ((unsigned int)(r0 + cx1) << 16);
        ip[2*p + 1] = (unsigned int)(r1 + cx0) | ((unsigned int)(r1 + cx1) << 16);
        wcs[4*p]     = wx0 * wy0;
        wcs[4*p + 1] = wx1 * wy0;
        wcs[4*p + 2] = wx0 * wy1;
        wcs[4*p + 3] = wx1 * wy1;
    }

    f32x2 acc2[4];
#pragma unroll
    for (int c = 0; c < 4; ++c) { acc2[c][0] = 0.f; acc2[c][1] = 0.f; }

#define GATHER(i_, w_) do { \
        const uint4 g_ = *(const uint4*)(vbase + ((size_t)(i_) << 8)); \
        f32x2 gw_; gw_[0] = (w_); gw_[1] = (w_); \
        f32x2 gp_; \
        gp_[0] = __uint_as_float(g_.x << 16); gp_[1] = __uint_as_float(g_.x & 0xffff0000u); \
        acc2[0] = __builtin_elementwise_fma(gw_, gp_, acc2[0]); \
        gp_[0] = __uint_as_float(g_.y << 16); gp_[1] = __uint_as_float(g_.y & 0xffff0000u); \
        acc2[1] = __builtin_elementwise_fma(gw_, gp_, acc2[1]); \
        gp_[0] = __uint_as_float(g_.z << 16); gp_[1] = __uint_as_float(g_.z & 0xffff0000u); \
        acc2[2] = __builtin_elementwise_fma(gw_, gp_, acc2[2]); \
        gp_[0] = __uint_as_float(g_.w << 16); gp_[1] = __uint_as_float(g_.w & 0xffff0000u); \
        acc2[3] = __builtin_elementwise_fma(gw_, gp_, acc2[3]); \
    } while (0)

#define POINT(L, p) do { \
        const unsigned int pk0_ = (unsigned int)dppi<(L)*85>((int)ip[2*(p)]); \
        const unsigned int pk1_ = (unsigned int)dppi<(L)*85>((int)ip[2*(p)+1]); \
        const float cw0_ = dppf<(L)*85>(wcs[4*(p)]); \
        const float cw1_ = dppf<(L)*85>(wcs[4*(p)+1]); \
        const float cw2_ = dppf<(L)*85>(wcs[4*(p)+2]); \
        const float cw3_ = dppf<(L)*85>(wcs[4*(p)+3]); \
        GATHER(pk0_ & 0xffffu, cw0_); \
        GATHER(pk0_ >> 16,     cw1_); \
        GATHER(pk1_ & 0xffffu, cw2_); \
        GATHER(pk1_ >> 16,     cw3_); \
    } while (0)

#define LEVEL(L) do { POINT(L,0); POINT(L,1); POINT(L,2); POINT(L,3); } while (0)

    LEVEL(0); LEVEL(1); LEVEL(2); LEVEL(3);

#undef LEVEL
#undef POINT
#undef GATHER

    uint4 o;
    o.x = pk2(acc2[0][0], acc2[0][1]); o.y = pk2(acc2[1][0], acc2[1][1]);
    o.z = pk2(acc2[2][0], acc2[2][1]); o.w = pk2(acc2[3][0], acc2[3][1]);
    *(uint4*)(out + (size_t)row * D + ch) = o;
}

// ---------------------------------------------------------------------
// out = LayerNorm(a + b) * g + beta over D=256. ONE WAVE per row.
// ---------------------------------------------------------------------
__global__ __launch_bounds__(256) void add_ln(const float* a, const float* b,
                                              const float* __restrict__ g,
                                              const float* __restrict__ be,
                                              const float* __restrict__ pos,
                                              float* out, unsigned short* outb)
{
    const int lane = threadIdx.x & 63;
    const int row  = blockIdx.x * 4 + (threadIdx.x >> 6);
    if (row >= NROWS) return;
    const size_t base = (size_t)row * D + (lane << 2);
    const float4 av = *(const float4*)(a + base);
    const float4 bv = *(const float4*)(b + base);
    float4 v = make_float4(av.x + bv.x, av.y + bv.y, av.z + bv.z, av.w + bv.w);
    float s = v.x + v.y + v.z + v.w;
#pragma unroll
    for (int off = 1; off < 64; off <<= 1) s += __shfl_xor(s, off);
    const float mean = s * (1.f / 256.f);
    const float4 d = make_float4(v.x - mean, v.y - mean, v.z - mean, v.w - mean);
    float q = d.x*d.x + d.y*d.y + d.z*d.z + d.w*d.w;
#pragma unroll
    for (int off = 1; off < 64; off <<= 1) q += __shfl_xor(q, off);
    const float rstd = rsqrtf(q * (1.f / 256.f) + 1e-5f);
    const float4 gv = *(const float4*)(g  + (lane << 2));
    const float4 bev = *(const float4*)(be + (lane << 2));
    float4 o;
    o.x = d.x * rstd * gv.x + bev.x;
    o.y = d.y * rstd * gv.y + bev.y;
    o.z = d.z * rstd * gv.z + bev.z;
    o.w = d.w * rstd * gv.w + bev.w;
    *(float4*)(out + base) = o;
    if (outb) {
        float4 p = make_float4(0.f, 0.f, 0.f, 0.f);
        if (pos) p = *(const float4*)(pos + base);
        uint2 u;
        u.x = pk2(o.x + p.x, o.y + p.y);
        u.y = pk2(o.z + p.z, o.w + p.w);
        *(uint2*)(outb + base) = u;
    }
}

// ---------------------------------------------------------------------
// text K/V projections + text passthrough output (fused).
// ---------------------------------------------------------------------
__global__ __launch_bounds__(256) void text_kv(const float* __restrict__ text,
                                               const float* __restrict__ ipw,
                                               const float* __restrict__ ipb,
                                               float* __restrict__ kh,
                                               float* __restrict__ vh,
                                               float* __restrict__ outtxt)
{
    __shared__ float ts[D];
    const int row = blockIdx.x, t = threadIdx.x;
    const float tv = text[(size_t)row * D + t];
    ts[t] = tv;
    outtxt[(size_t)row * D + t] = tv;
    __syncthreads();
    const float* wk = ipw + (size_t)(D + t) * D;
    const float* wv = ipw + (size_t)(2 * D + t) * D;
    float sk = ipb[D + t], sv = ipb[2 * D + t];
    for (int k = 0; k < D; ++k) {
        sk = fmaf(ts[k], wk[k], sk);
        sv = fmaf(ts[k], wv[k], sv);
    }
    kh[(size_t)row * D + t] = sk;
    vh[(size_t)row * D + t] = sv;
}

// ---------------------------------------------------------------------
// cross-attention to text: 8 query rows per block; V + 8 q-rows staged in
// LDS once; K-fragment and V-column hoisted to registers and reused.
// grid: (ceil(LQ/8), B)
// ---------------------------------------------------------------------
__global__ __launch_bounds__(256) void text_attn(const float* __restrict__ qh,
                                                 const float* __restrict__ kh,
                                                 const float* __restrict__ vh,
                                                 unsigned short* __restrict__ ctx)
{
    __shared__ float vs[LT * D];      // 20 KB
    __shared__ float qs[8][D];        // 8 KB
    const int b  = blockIdx.y;
    const int q0 = blockIdx.x * 8;
    const int t  = threadIdx.x;
    const int nr = min(8, LQ - q0);

    {
        const float4* vsrc = (const float4*)(vh + (size_t)b * LT * D);
        float4* vdst = (float4*)vs;
#pragma unroll
        for (int i = 0; i < 5; ++i) vdst[t + 256 * i] = vsrc[t + 256 * i];
        for (int r = 0; r < nr; ++r)
            qs[r][t] = qh[((size_t)b * LQ + q0 + r) * D + t];
    }
    __syncthreads();

    const int h = t >> 5, d = t & 31;
    const int lane = t & 63;
    float kf[32];
    if (d < LT) {
        const float4* kr = (const float4*)(kh + (size_t)(b * LT + d) * D + h * HDIM);
#pragma unroll
        for (int i = 0; i < 8; ++i) {
            const float4 kv = kr[i];
            kf[4*i] = kv.x; kf[4*i+1] = kv.y; kf[4*i+2] = kv.z; kf[4*i+3] = kv.w;
        }
    }
    float vv[LT];
#pragma unroll
    for (int k = 0; k < LT; ++k) vv[k] = vs[k * D + t];

    for (int r = 0; r < nr; ++r) {
        float sc = -1e30f;
        if (d < LT) {
            const float4* qq = (const float4*)(qs[r] + h * HDIM);
            float s = 0.f;
#pragma unroll
            for (int i = 0; i < 8; ++i) {
                const float4 qv = qq[i];
                s = fmaf(qv.x, kf[4*i],   s); s = fmaf(qv.y, kf[4*i+1], s);
                s = fmaf(qv.z, kf[4*i+2], s); s = fmaf(qv.w, kf[4*i+3], s);
            }
            sc = s * 0.17677669529663687f;   // 1/sqrt(32)
        }
        float mx = sc;
#pragma unroll
        for (int off = 1; off < 32; off <<= 1) mx = fmaxf(mx, __shfl_xor(mx, off));
        const float e = (d < LT) ? __expf(sc - mx) : 0.f;
        float sm = e;
#pragma unroll
        for (int off = 1; off < 32; off <<= 1) sm += __shfl_xor(sm, off);
        const float pr = e * (1.f / sm);
        float o0 = 0.f, o1 = 0.f;
#pragma unroll
        for (int k = 0; k < LT; k += 2) {
            const float p0 = __shfl(pr, (lane & 32) | k);
            const float p1 = __shfl(pr, (lane & 32) | (k + 1));
            o0 = fmaf(p0, vv[k],     o0);
            o1 = fmaf(p1, vv[k + 1], o1);
        }
        ctx[((size_t)b * LQ + q0 + r) * D + t] = f2b(o0 + o1);
    }
}

// =====================================================================
extern "C" void kernel_launch(void* const* d_in, const int* in_sizes, int n_in,
                              void* d_out, int out_size, void* d_ws, size_t ws_size,
                              hipStream_t stream)
{
    const float* src  = (const float*)d_in[0];
    const float* pos  = (const float*)d_in[1];
    const float* refp = (const float*)d_in[2];
    const float* text = (const float*)d_in[5];
    const float* so_w = (const float*)d_in[7];
    const float* so_b = (const float*)d_in[8];
    const float* aw_w = (const float*)d_in[9];
    const float* aw_b = (const float*)d_in[10];
    const float* vp_w = (const float*)d_in[11];
    const float* vp_b = (const float*)d_in[12];
    const float* op_w = (const float*)d_in[13];
    const float* op_b = (const float*)d_in[14];
    const float* ln1g = (const float*)d_in[15];
    const float* ln1b = (const float*)d_in[16];
    const float* ipw  = (const float*)d_in[17];
    const float* ipb  = (const float*)d_in[18];
    const float* mow  = (const float*)d_in[19];
    const float* mob  = (const float*)d_in[20];
    const float* ln3g = (const float*)d_in[21];
    const float* ln3b = (const float*)d_in[22];
    const float* l1w  = (const float*)d_in[23];
    const float* l1b  = (const float*)d_in[24];
    const float* l2w  = (const float*)d_in[25];
    const float* l2b  = (const float*)d_in[26];
    const float* ln2g = (const float*)d_in[27];
    const float* ln2b = (const float*)d_in[28];

    float* ws = (float*)d_ws;
    float*          oa     = ws;
    unsigned short* srcb   = (unsigned short*)(ws + SFL + SFL / 2);
    unsigned short* mscb   = srcb;
    unsigned short* qbf    = (unsigned short*)(ws + 2 * SFL);
    unsigned short* valb   = (unsigned short*)(ws + 2 * SFL + SFL / 2);
    float*          gen32  = ws + 3 * SFL;
    float*          x12    = ws + 4 * SFL;
    unsigned short* wb     = (unsigned short*)(ws + 5 * SFL);
    unsigned short* hidden = (unsigned short*)ws;   // N x 1024 bf16 overlays [0,2.0)

    unsigned short* wb_vp = wb;
    unsigned short* wb_so = wb + 65536;             // so(256 rows) then aw(128 rows)
    unsigned short* wb_aw = wb + 131072;
    unsigned short* wb_op = wb + 163840;
    unsigned short* wb_wq = wb + 229376;
    unsigned short* wb_mo = wb + 294912;
    unsigned short* wb_l1 = wb + 360448;
    unsigned short* wb_l2 = wb + 622592;            // end 884736 shorts
    float* kvk  = ws + 5 * SFL + 442368;
    float* kvv  = kvk + (size_t)BB * LT * D;
    float* sobc = kvv + (size_t)BB * LT * D;

    const int M = NROWS;
    const int gx   = (M + 127) / 128;               // 316
    const int gx64 = (M + 63) / 64;                 // 632
    const dim3 blk(256);
    const int n4 = (int)(SFL / 4);
    const int vgrid = (n4 + 255) / 256;
    const int dgrid = (M + 7) / 8;
    const int lgrid = (M + 3) / 4;

    // 0. weight casts
    W8 w8;
    w8.s[0] = vp_w; w8.d[0] = wb_vp; w8.n[0] = 65536;
    w8.s[1] = so_w; w8.d[1] = wb_so; w8.n[1] = 65536;
    w8.s[2] = aw_w; w8.d[2] = wb_aw; w8.n[2] = 32768;
    w8.s[3] = op_w; w8.d[3] = wb_op; w8.n[3] = 65536;
    w8.s[4] = ipw;  w8.d[4] = wb_wq; w8.n[4] = 65536;
    w8.s[5] = mow;  w8.d[5] = wb_mo; w8.n[5] = 65536;
    w8.s[6] = l1w;  w8.d[6] = wb_l1; w8.n[6] = 262144;
    w8.s[7] = l2w;  w8.d[7] = wb_l2; w8.n[7] = 262144;
    cast_w8<<<dim3(128, 8), blk, 0, stream>>>(w8);
    cat_bias<<<dim3(1), dim3(384), 0, stream>>>(so_b, aw_b, sobc);
    // 1. srcb = bf16(src), qbf = bf16(src+pos)
    cast_pair<<<dim3(vgrid), blk, 0, stream>>>((const float4*)src, (const float4*)pos,
                                               (ushort4*)srcb, (ushort4*)qbf, n4);
    // 2. value = src @ vp^T + b -> bf16   [64-row tiles: 1264 blocks]
    gemm_mfma64<<<dim3(gx64, 2), blk, 0, stream>>>(srcb, wb_vp, vp_b, nullptr, valb, M, 256, 256, 0);
    // 3. merged offs+logits = q @ [so;aw]^T + b -> oa fp32 (N x 384)  [1896 blocks]
    gemm_mfma64<<<dim3(gx64, 3), blk, 0, stream>>>(qbf, wb_so, sobc, oa, nullptr, M, 384, 256, 0);
    // 4. deformable sampling (softmax fused) -> mscore bf16
    msdeform<<<dim3(dgrid), blk, 0, stream>>>(valb, oa, refp, mscb);
    // 5. ms = mscore @ op^T + b -> fp32
    gemm_mfma64<<<dim3(gx64, 2), blk, 0, stream>>>(mscb, wb_op, op_b, gen32, nullptr, M, 256, 256, 0);
    // 6. x1 = LN(src + ms) -> x12; q2 = bf16(x1 + pos) -> qbf (fused)
    add_ln<<<dim3(lgrid), blk, 0, stream>>>(src, gen32, ln1g, ln1b, pos, x12, qbf);
    // 7. text K/V + text passthrough out (fused)
    float* outx = (float*)d_out;
    text_kv<<<dim3(BB * LT), blk, 0, stream>>>(text, ipw, ipb, kvk, kvv, outx + SFL);
    // 8. qh = q2 @ wq^T + bq -> fp32
    gemm_mfma64<<<dim3(gx64, 2), blk, 0, stream>>>(qbf, wb_wq, ipb, gen32, nullptr, M, 256, 256, 0);
    // 9. ctx = attn(qh, K, V) -> bf16 (qbf reused)
    text_attn<<<dim3((LQ + 7) / 8, BB), blk, 0, stream>>>(gen32, kvk, kvv, qbf);
    // 10. mha = ctx @ mow^T + b -> fp32
    gemm_mfma64<<<dim3(gx64, 2), blk, 0, stream>>>(qbf, wb_mo, mob, gen32, nullptr, M, 256, 256, 0);
    // 11. x2 = LN(x1 + mha) -> x12 in-place; bf16 copy -> qbf
    add_ln<<<dim3(lgrid), blk, 0, stream>>>(x12, gen32, ln3g, ln3b, nullptr, x12, qbf);
    // 12. hidden = relu(x2 @ l1^T + b) -> bf16   [N=1024: grid already 2528]
    gemm_mfma<<<dim3(gx, 8), blk, 0, stream>>>(qbf, wb_l1, l1b, nullptr, hidden, M, 1024, 256, 1);
    // 13. ffn = hidden @ l2^T + b -> d_out (fp32 scratch)   [64-row tiles, K=1024]
    gemm_mfma64<<<dim3(gx64, 2), blk, 0, stream>>>(hidden, wb_l2, l2b, outx, nullptr, M, 256, 1024, 0);
    // 14. x3 = LN(x2 + ffn) -> d_out
    add_ln<<<dim3(lgrid), blk, 0, stream>>>(x12, outx, ln2g, ln2b, nullptr, outx, nullptr);
}

// Round 8
// 651.931 us; speedup vs baseline: 1.0477x; 1.0477x over previous
//
#include <hip/hip_runtime.h>
#include <math.h>

// ---------------- problem constants ----------------
#define D     256
#define NH    8
#define HDIM  32
#define NL    4
#define NPT   4
#define DFF   1024
#define BB    2
#define LT    20
#define LQ    20197
#define NROWS (BB*LQ)                 // 40394
#define SFL   ((size_t)NROWS * D)     // floats per N x 256 buffer

typedef __attribute__((ext_vector_type(8))) short bf16x8;
typedef __attribute__((ext_vector_type(4))) float f32x4;

__device__ __forceinline__ unsigned short f2b(float f) {
    unsigned int u = __float_as_uint(f);
    unsigned int r = (u + 0x7FFFu + ((u >> 16) & 1u)) >> 16;   // RNE
    return (unsigned short)r;
}
__device__ __forceinline__ float b2f(unsigned short u) {
    return __uint_as_float((unsigned int)u << 16);
}
__device__ __forceinline__ unsigned int pk2(float a, float b) {
    return (unsigned int)f2b(a) | ((unsigned int)f2b(b) << 16);
}

// DPP quad_perm helpers (compile-time control). Broadcast-from-quad-lane-L
// control word is L*0b01010101 = L*85. xor1 = 0xB1, xor2 = 0x4E.
template<int CTRL>
__device__ __forceinline__ int dppi(int v) {
    return __builtin_amdgcn_update_dpp(0, v, CTRL, 0xF, 0xF, true);
}
template<int CTRL>
__device__ __forceinline__ float dppf(float v) {
    return __uint_as_float((unsigned int)__builtin_amdgcn_update_dpp(
        0, (int)__float_as_uint(v), CTRL, 0xF, 0xF, true));
}

#define GLDS16(g, l) __builtin_amdgcn_global_load_lds( \
    (const __attribute__((address_space(1))) unsigned int*)(g), \
    (__attribute__((address_space(3))) unsigned int*)(l), 16, 0, 0)

// =====================================================================
// bf16 MFMA GEMM (128x128 tile): used only where grid is already large
// (step 12: N=1024 -> 2528 blocks). 4 waves (2x2 of 64x64), dbuf.
// =====================================================================
__global__ __launch_bounds__(256) void gemm_mfma(const unsigned short* __restrict__ A,
                                                 const unsigned short* __restrict__ W,
                                                 const float* __restrict__ bias,
                                                 float* __restrict__ Cf,
                                                 unsigned short* __restrict__ Cb,
                                                 int M, int Nout, int K, int relu)
{
    __shared__ __align__(16) unsigned short As[2][128 * 32];   // 2 x 8 KB
    __shared__ __align__(16) unsigned short Ws[2][128 * 32];   // 2 x 8 KB
    const int tid  = threadIdx.x;
    const int wave = tid >> 6, lane = tid & 63;
    const int row0 = blockIdx.x * 128, n0 = blockIdx.y * 128;
    const int wm = (wave >> 1) * 64, wn = (wave & 1) * 64;

    const int srow = (wave << 5) + (lane >> 2);
    const int kcol = (lane & 3) << 3;
    const int ar0 = min(row0 + srow,      M - 1);
    const int ar1 = min(row0 + srow + 16, M - 1);
    const unsigned short* Ap0 = A + (size_t)ar0 * K + kcol;
    const unsigned short* Ap1 = A + (size_t)ar1 * K + kcol;
    const unsigned short* Wp0 = W + (size_t)(n0 + srow) * K + kcol;
    const unsigned short* Wp1 = W + (size_t)(n0 + srow + 16) * K + kcol;
    const int aoff0 = (wave << 10);          // per-wave staging offset (shorts)
    const int aoff1 = (wave << 10) + 512;

    f32x4 acc[4][4];
#pragma unroll
    for (int i = 0; i < 4; ++i)
#pragma unroll
        for (int j = 0; j < 4; ++j)
#pragma unroll
            for (int r = 0; r < 4; ++r) acc[i][j][r] = 0.f;

    const int fr = lane & 15;
    const int fk = (lane >> 4) << 3;

    // prologue: stage tile 0 into buffer 0
    GLDS16(Ap0, &As[0][aoff0]);
    GLDS16(Ap1, &As[0][aoff1]);
    GLDS16(Wp0, &Ws[0][aoff0]);
    GLDS16(Wp1, &Ws[0][aoff1]);
    __syncthreads();

    const int nt = K >> 5;
    int cur = 0;
    for (int t = 0; t < nt; ++t) {
        if (t + 1 < nt) {
            const int k1 = (t + 1) << 5;
            GLDS16(Ap0 + k1, &As[cur ^ 1][aoff0]);
            GLDS16(Ap1 + k1, &As[cur ^ 1][aoff1]);
            GLDS16(Wp0 + k1, &Ws[cur ^ 1][aoff0]);
            GLDS16(Wp1 + k1, &Ws[cur ^ 1][aoff1]);
        }
        bf16x8 af[4], wf[4];
#pragma unroll
        for (int t4 = 0; t4 < 4; ++t4) {
            af[t4] = *(const bf16x8*)&As[cur][(wm + t4 * 16 + fr) * 32 + fk];
            wf[t4] = *(const bf16x8*)&Ws[cur][(wn + t4 * 16 + fr) * 32 + fk];
        }
#pragma unroll
        for (int i = 0; i < 4; ++i)
#pragma unroll
            for (int j = 0; j < 4; ++j)
                acc[i][j] = __builtin_amdgcn_mfma_f32_16x16x32_bf16(af[i], wf[j], acc[i][j], 0, 0, 0);
        __syncthreads();
        cur ^= 1;
    }

    const int rq = (lane >> 4) << 2;
    const int cq = lane & 15;
#pragma unroll
    for (int mt = 0; mt < 4; ++mt) {
#pragma unroll
        for (int r = 0; r < 4; ++r) {
            const int row = row0 + wm + mt * 16 + rq + r;
            if (row < M) {
#pragma unroll
                for (int nt2 = 0; nt2 < 4; ++nt2) {
                    const int c = n0 + wn + nt2 * 16 + cq;
                    float v = acc[mt][nt2][r] + bias[c];
                    if (relu) v = fmaxf(v, 0.f);
                    if (Cb) Cb[(size_t)row * Nout + c] = f2b(v);
                    else    Cf[(size_t)row * Nout + c] = v;
                }
            }
        }
    }
}

// =====================================================================
// bf16 MFMA GEMM, 64x128 tile — thin GEMMs (r5: grid-starvation fix, -32us).
// r8: reverted to the proven r5 form (BK=32, 2 barriers/step) — the r6/r7
// BK=64 variant regressed ~+20us (r7 post-mortem).
// 4 waves, wave w owns all 64 rows x cols [32w,32w+32). LDS 12 KB.
// =====================================================================
__global__ __launch_bounds__(256) void gemm_mfma64(const unsigned short* __restrict__ A,
                                                   const unsigned short* __restrict__ W,
                                                   const float* __restrict__ bias,
                                                   float* __restrict__ Cf,
                                                   unsigned short* __restrict__ Cb,
                                                   int M, int Nout, int K, int relu)
{
    __shared__ __align__(16) unsigned short As[64 * 32];     // 4 KB
    __shared__ __align__(16) unsigned short Ws[128 * 32];    // 8 KB
    const int tid  = threadIdx.x;
    const int wave = tid >> 6, lane = tid & 63;
    const int row0 = blockIdx.x * 64, n0 = blockIdx.y * 128;
    const int wn = wave << 5;                 // col offset 0/32/64/96

    // staging: wave v stages A rows [16v,16v+16) and W rows [32v,32v+32)
    const int srow = lane >> 2;
    const int kcol = (lane & 3) << 3;
    const int arow = min(row0 + (wave << 4) + srow, M - 1);
    const unsigned short* Ap  = A + (size_t)arow * K + kcol;
    const unsigned short* Wp0 = W + (size_t)(n0 + (wave << 5) + srow) * K + kcol;
    const unsigned short* Wp1 = W + (size_t)(n0 + (wave << 5) + 16 + srow) * K + kcol;
    unsigned short* lA  = &As[wave << 9];     // 16 rows * 32 = 512 shorts/wave
    unsigned short* lW0 = &Ws[wave << 10];    // 32 rows * 32 = 1024 shorts/wave
    unsigned short* lW1 = &Ws[(wave << 10) + 512];

    f32x4 acc[4][2];
#pragma unroll
    for (int i = 0; i < 4; ++i)
#pragma unroll
        for (int j = 0; j < 2; ++j)
#pragma unroll
            for (int r = 0; r < 4; ++r) acc[i][j][r] = 0.f;

    const int fr = lane & 15;
    const int fk = (lane >> 4) << 3;

    for (int k0 = 0; k0 < K; k0 += 32) {
        GLDS16(Ap + k0, lA);
        GLDS16(Wp0 + k0, lW0);
        GLDS16(Wp1 + k0, lW1);
        __syncthreads();
        bf16x8 af[4], wf[2];
#pragma unroll
        for (int i = 0; i < 4; ++i)
            af[i] = *(const bf16x8*)&As[(i * 16 + fr) * 32 + fk];
#pragma unroll
        for (int j = 0; j < 2; ++j)
            wf[j] = *(const bf16x8*)&Ws[(wn + j * 16 + fr) * 32 + fk];
#pragma unroll
        for (int i = 0; i < 4; ++i)
#pragma unroll
            for (int j = 0; j < 2; ++j)
                acc[i][j] = __builtin_amdgcn_mfma_f32_16x16x32_bf16(af[i], wf[j], acc[i][j], 0, 0, 0);
        __syncthreads();
    }

    const int rq = (lane >> 4) << 2;
    const int cq = lane & 15;
#pragma unroll
    for (int i = 0; i < 4; ++i) {
#pragma unroll
        for (int r = 0; r < 4; ++r) {
            const int row = row0 + i * 16 + rq + r;
            if (row < M) {
#pragma unroll
                for (int j = 0; j < 2; ++j) {
                    const int c = n0 + wn + j * 16 + cq;
                    float v = acc[i][j][r] + bias[c];
                    if (relu) v = fmaxf(v, 0.f);
                    if (Cb) Cb[(size_t)row * Nout + c] = f2b(v);
                    else    Cf[(size_t)row * Nout + c] = v;
                }
            }
        }
    }
}

// ---------------------------------------------------------------------
// batched fp32 -> bf16 weight cast (8 segments)
// ---------------------------------------------------------------------
struct W8 {
    const float* s[8];
    unsigned short* d[8];
    int n[8];
};
__global__ __launch_bounds__(256) void cast_w8(W8 w)
{
    const int seg = blockIdx.y;
    const int n = w.n[seg];
    const float* s = w.s[seg];
    unsigned short* d = w.d[seg];
    for (int i = blockIdx.x * 256 + threadIdx.x; i < n; i += gridDim.x * 256)
        d[i] = f2b(s[i]);
}

// concat so_b(256) + aw_b(128) -> o(384)
__global__ __launch_bounds__(384) void cat_bias(const float* __restrict__ sb,
                                                const float* __restrict__ ab,
                                                float* __restrict__ o)
{
    const int t = threadIdx.x;
    o[t] = (t < 256) ? sb[t] : ab[t - 256];
}

// srcb = bf16(src); qbf = bf16(src + pos)    (one pass)
__global__ __launch_bounds__(256) void cast_pair(const float4* __restrict__ src,
                                                 const float4* __restrict__ pos,
                                                 ushort4* __restrict__ srcb,
                                                 ushort4* __restrict__ qbf, int n4)
{
    const int i = blockIdx.x * 256 + threadIdx.x;
    if (i < n4) {
        const float4 s = src[i], p = pos[i];
        srcb[i] = make_ushort4(f2b(s.x), f2b(s.y), f2b(s.z), f2b(s.w));
        qbf[i]  = make_ushort4(f2b(s.x + p.x), f2b(s.y + p.y), f2b(s.z + p.z), f2b(s.w + p.w));
    }
}

// ---------------------------------------------------------------------
// multi-scale deformable sampling v8 = r5's v6 body (92 us, VGPR 40 —
// the r7 packed-fma variant REGRESSED via occupancy/L1-thrash; reverted)
// + XCD-aware BIJECTIVE block swizzle (T1, m204 form; dgrid%8 != 0):
// consecutive blocks process raster-adjacent query rows with overlapping
// value footprints; chunked mapping gives each XCD L2 a contiguous ~1/8
// of the rows instead of round-robin duplication across 8 L2s.
// ---------------------------------------------------------------------
#define SEL4(a0,a1,a2,a3) (j < 2 ? (j == 0 ? (a0) : (a1)) : (j == 2 ? (a2) : (a3)))

__global__ __launch_bounds__(256) void msdeform(const unsigned short* __restrict__ value,
                                                const float* __restrict__ oa,
                                                const float* __restrict__ refp,
                                                unsigned short* __restrict__ out)
{
    // bijective XCD swizzle: xcd = orig%8 gets chunk of q(+1) consecutive ids
    const int nwg  = gridDim.x;
    const int orig = blockIdx.x;
    const int xcd  = orig & 7;
    const int qch  = nwg >> 3, rch = nwg & 7;
    const int bid  = (xcd < rch ? xcd * (qch + 1) : rch * (qch + 1) + (xcd - rch) * qch)
                   + (orig >> 3);

    const int tid  = threadIdx.x;
    const int lane = tid & 63;
    const int row  = bid * 8 + ((tid >> 6) << 1) + (lane >> 5);
    if (row >= NROWS) return;
    const int b   = row / LQ;
    const int sub = lane & 31;
    const int h   = sub >> 2;
    const int j   = sub & 3;                 // this lane's level AND channel-chunk
    const int ch  = (h << 5) + (j << 3);
    const unsigned short* vbase = value + (size_t)b * LQ * D + ch;

    const float* orow = oa + (size_t)row * 384;
    const float4 o0 = *(const float4*)(orow + (h << 5) + (j << 3));
    const float4 o1 = *(const float4*)(orow + (h << 5) + (j << 3) + 4);
    const float oxr[4] = {o0.x, o0.z, o1.x, o1.z};
    const float oyr[4] = {o0.y, o0.w, o1.y, o1.w};
    const float4 lg = *(const float4*)(orow + 256 + (h << 4) + (j << 2));
    float mx = fmaxf(fmaxf(lg.x, lg.y), fmaxf(lg.z, lg.w));
    mx = fmaxf(mx, dppf<0xB1>(mx));
    mx = fmaxf(mx, dppf<0x4E>(mx));
    const float e0 = __expf(lg.x - mx), e1 = __expf(lg.y - mx);
    const float e2 = __expf(lg.z - mx), e3 = __expf(lg.w - mx);
    float sm = e0 + e1 + e2 + e3;
    sm += dppf<0xB1>(sm);
    sm += dppf<0x4E>(sm);
    const float inv = 1.f / sm;
    const float pr[4] = {e0 * inv, e1 * inv, e2 * inv, e3 * inv};

    const int   Wi   = SEL4(152, 76, 38, 19);
    const int   Hi   = SEL4(100, 50, 25, 13);
    const int   st   = SEL4(0, 15200, 19000, 19950);
    const float invW = SEL4(1.f/152.f, 1.f/76.f, 1.f/38.f, 1.f/19.f);
    const float invH = SEL4(1.f/100.f, 1.f/50.f, 1.f/25.f, 1.f/13.f);
    const float Wf = (float)Wi, Hf = (float)Hi;
    const float2 rxy = *(const float2*)(refp + (size_t)row * 8 + (j << 1));

    unsigned int ip[8];
    float wcs[16];
#pragma unroll
    for (int p = 0; p < 4; ++p) {
        const float x = fmaf(oxr[p], invW, rxy.x) * Wf - 0.5f;
        const float y = fmaf(oyr[p], invH, rxy.y) * Hf - 0.5f;
        const float x0f = floorf(x), y0f = floorf(y);
        const float lx = x - x0f, ly = y - y0f;
        const int x0 = (int)x0f, y0 = (int)y0f;
        const int x1 = x0 + 1,  y1 = y0 + 1;
        const float vx0 = (x0 >= 0 && x0 < Wi) ? 1.f : 0.f;
        const float vx1 = (x1 >= 0 && x1 < Wi) ? 1.f : 0.f;
        const float vy0 = (y0 >= 0 && y0 < Hi) ? 1.f : 0.f;
        const float vy1 = (y1 >= 0 && y1 < Hi) ? 1.f : 0.f;
        const int cx0 = min(max(x0, 0), Wi - 1), cx1 = min(max(x1, 0), Wi - 1);
        const int cy0 = min(max(y0, 0), Hi - 1), cy1 = min(max(y1, 0), Hi - 1);
        const float wap = pr[p];
        const float wx0 = (1.f - lx) * vx0,        wx1 = lx * vx1;
        const float wy0 = (1.f - ly) * vy0 * wap,  wy1 = ly * vy1 * wap;
        const int r0 = st + cy0 * Wi, r1 = st + cy1 * Wi;
        ip[2*p]     = (unsigned int)(r0 + cx0) | ((unsigned int)(r0 + cx1) << 16);
        ip[2*p + 1] = (unsigned int)(r1 + cx0) | ((unsigned int)(r1 + cx1) << 16);
        wcs[4*p]     = wx0 * wy0;
        wcs[4*p + 1] = wx1 * wy0;
        wcs[4*p + 2] = wx0 * wy1;
        wcs[4*p + 3] = wx1 * wy1;
    }

    float acc[8] = {0.f,0.f,0.f,0.f,0.f,0.f,0.f,0.f};

#define GATHER(i_, w_) do { \
        const uint4 g_ = *(const uint4*)(vbase + ((size_t)(i_) << 8)); \
        acc[0] = fmaf(w_, __uint_as_float(g_.x << 16),          acc[0]); \
        acc[1] = fmaf(w_, __uint_as_float(g_.x & 0xffff0000u),  acc[1]); \
        acc[2] = fmaf(w_, __uint_as_float(g_.y << 16),          acc[2]); \
        acc[3] = fmaf(w_, __uint_as_float(g_.y & 0xffff0000u),  acc[3]); \
        acc[4] = fmaf(w_, __uint_as_float(g_.z << 16),          acc[4]); \
        acc[5] = fmaf(w_, __uint_as_float(g_.z & 0xffff0000u),  acc[5]); \
        acc[6] = fmaf(w_, __uint_as_float(g_.w << 16),          acc[6]); \
        acc[7] = fmaf(w_, __uint_as_float(g_.w & 0xffff0000u),  acc[7]); \
    } while (0)

#define POINT(L, p) do { \
        const unsigned int pk0_ = (unsigned int)dppi<(L)*85>((int)ip[2*(p)]); \
        const unsigned int pk1_ = (unsigned int)dppi<(L)*85>((int)ip[2*(p)+1]); \
        const float cw0_ = dppf<(L)*85>(wcs[4*(p)]); \
        const float cw1_ = dppf<(L)*85>(wcs[4*(p)+1]); \
        const float cw2_ = dppf<(L)*85>(wcs[4*(p)+2]); \
        const float cw3_ = dppf<(L)*85>(wcs[4*(p)+3]); \
        GATHER(pk0_ & 0xffffu, cw0_); \
        GATHER(pk0_ >> 16,     cw1_); \
        GATHER(pk1_ & 0xffffu, cw2_); \
        GATHER(pk1_ >> 16,     cw3_); \
    } while (0)

#define LEVEL(L) do { POINT(L,0); POINT(L,1); POINT(L,2); POINT(L,3); } while (0)

    LEVEL(0); LEVEL(1); LEVEL(2); LEVEL(3);

#undef LEVEL
#undef POINT
#undef GATHER

    uint4 o;
    o.x = pk2(acc[0], acc[1]); o.y = pk2(acc[2], acc[3]);
    o.z = pk2(acc[4], acc[5]); o.w = pk2(acc[6], acc[7]);
    *(uint4*)(out + (size_t)row * D + ch) = o;
}

// ---------------------------------------------------------------------
// out = LayerNorm(a + b) * g + beta over D=256. ONE WAVE per row.
// ---------------------------------------------------------------------
__global__ __launch_bounds__(256) void add_ln(const float* a, const float* b,
                                              const float* __restrict__ g,
                                              const float* __restrict__ be,
                                              const float* __restrict__ pos,
                                              float* out, unsigned short* outb)
{
    const int lane = threadIdx.x & 63;
    const int row  = blockIdx.x * 4 + (threadIdx.x >> 6);
    if (row >= NROWS) return;
    const size_t base = (size_t)row * D + (lane << 2);
    const float4 av = *(const float4*)(a + base);
    const float4 bv = *(const float4*)(b + base);
    float4 v = make_float4(av.x + bv.x, av.y + bv.y, av.z + bv.z, av.w + bv.w);
    float s = v.x + v.y + v.z + v.w;
#pragma unroll
    for (int off = 1; off < 64; off <<= 1) s += __shfl_xor(s, off);
    const float mean = s * (1.f / 256.f);
    const float4 d = make_float4(v.x - mean, v.y - mean, v.z - mean, v.w - mean);
    float q = d.x*d.x + d.y*d.y + d.z*d.z + d.w*d.w;
#pragma unroll
    for (int off = 1; off < 64; off <<= 1) q += __shfl_xor(q, off);
    const float rstd = rsqrtf(q * (1.f / 256.f) + 1e-5f);
    const float4 gv = *(const float4*)(g  + (lane << 2));
    const float4 bev = *(const float4*)(be + (lane << 2));
    float4 o;
    o.x = d.x * rstd * gv.x + bev.x;
    o.y = d.y * rstd * gv.y + bev.y;
    o.z = d.z * rstd * gv.z + bev.z;
    o.w = d.w * rstd * gv.w + bev.w;
    *(float4*)(out + base) = o;
    if (outb) {
        float4 p = make_float4(0.f, 0.f, 0.f, 0.f);
        if (pos) p = *(const float4*)(pos + base);
        uint2 u;
        u.x = pk2(o.x + p.x, o.y + p.y);
        u.y = pk2(o.z + p.z, o.w + p.w);
        *(uint2*)(outb + base) = u;
    }
}

// ---------------------------------------------------------------------
// text K/V projections + text passthrough output (fused).
// ---------------------------------------------------------------------
__global__ __launch_bounds__(256) void text_kv(const float* __restrict__ text,
                                               const float* __restrict__ ipw,
                                               const float* __restrict__ ipb,
                                               float* __restrict__ kh,
                                               float* __restrict__ vh,
                                               float* __restrict__ outtxt)
{
    __shared__ float ts[D];
    const int row = blockIdx.x, t = threadIdx.x;
    const float tv = text[(size_t)row * D + t];
    ts[t] = tv;
    outtxt[(size_t)row * D + t] = tv;
    __syncthreads();
    const float* wk = ipw + (size_t)(D + t) * D;
    const float* wv = ipw + (size_t)(2 * D + t) * D;
    float sk = ipb[D + t], sv = ipb[2 * D + t];
    for (int k = 0; k < D; ++k) {
        sk = fmaf(ts[k], wk[k], sk);
        sv = fmaf(ts[k], wv[k], sv);
    }
    kh[(size_t)row * D + t] = sk;
    vh[(size_t)row * D + t] = sv;
}

// ---------------------------------------------------------------------
// cross-attention to text: 8 query rows per block; V + 8 q-rows staged in
// LDS once; K-fragment and V-column hoisted to registers and reused.
// grid: (ceil(LQ/8), B)
// ---------------------------------------------------------------------
__global__ __launch_bounds__(256) void text_attn(const float* __restrict__ qh,
                                                 const float* __restrict__ kh,
                                                 const float* __restrict__ vh,
                                                 unsigned short* __restrict__ ctx)
{
    __shared__ float vs[LT * D];      // 20 KB
    __shared__ float qs[8][D];        // 8 KB
    const int b  = blockIdx.y;
    const int q0 = blockIdx.x * 8;
    const int t  = threadIdx.x;
    const int nr = min(8, LQ - q0);

    {
        const float4* vsrc = (const float4*)(vh + (size_t)b * LT * D);
        float4* vdst = (float4*)vs;
#pragma unroll
        for (int i = 0; i < 5; ++i) vdst[t + 256 * i] = vsrc[t + 256 * i];
        for (int r = 0; r < nr; ++r)
            qs[r][t] = qh[((size_t)b * LQ + q0 + r) * D + t];
    }
    __syncthreads();

    const int h = t >> 5, d = t & 31;
    const int lane = t & 63;
    float kf[32];
    if (d < LT) {
        const float4* kr = (const float4*)(kh + (size_t)(b * LT + d) * D + h * HDIM);
#pragma unroll
        for (int i = 0; i < 8; ++i) {
            const float4 kv = kr[i];
            kf[4*i] = kv.x; kf[4*i+1] = kv.y; kf[4*i+2] = kv.z; kf[4*i+3] = kv.w;
        }
    }
    float vv[LT];
#pragma unroll
    for (int k = 0; k < LT; ++k) vv[k] = vs[k * D + t];

    for (int r = 0; r < nr; ++r) {
        float sc = -1e30f;
        if (d < LT) {
            const float4* qq = (const float4*)(qs[r] + h * HDIM);
            float s = 0.f;
#pragma unroll
            for (int i = 0; i < 8; ++i) {
                const float4 qv = qq[i];
                s = fmaf(qv.x, kf[4*i],   s); s = fmaf(qv.y, kf[4*i+1], s);
                s = fmaf(qv.z, kf[4*i+2], s); s = fmaf(qv.w, kf[4*i+3], s);
            }
            sc = s * 0.17677669529663687f;   // 1/sqrt(32)
        }
        float mx = sc;
#pragma unroll
        for (int off = 1; off < 32; off <<= 1) mx = fmaxf(mx, __shfl_xor(mx, off));
        const float e = (d < LT) ? __expf(sc - mx) : 0.f;
        float sm = e;
#pragma unroll
        for (int off = 1; off < 32; off <<= 1) sm += __shfl_xor(sm, off);
        const float pr = e * (1.f / sm);
        float o0 = 0.f, o1 = 0.f;
#pragma unroll
        for (int k = 0; k < LT; k += 2) {
            const float p0 = __shfl(pr, (lane & 32) | k);
            const float p1 = __shfl(pr, (lane & 32) | (k + 1));
            o0 = fmaf(p0, vv[k],     o0);
            o1 = fmaf(p1, vv[k + 1], o1);
        }
        ctx[((size_t)b * LQ + q0 + r) * D + t] = f2b(o0 + o1);
    }
}

// =====================================================================
extern "C" void kernel_launch(void* const* d_in, const int* in_sizes, int n_in,
                              void* d_out, int out_size, void* d_ws, size_t ws_size,
                              hipStream_t stream)
{
    const float* src  = (const float*)d_in[0];
    const float* pos  = (const float*)d_in[1];
    const float* refp = (const float*)d_in[2];
    const float* text = (const float*)d_in[5];
    const float* so_w = (const float*)d_in[7];
    const float* so_b = (const float*)d_in[8];
    const float* aw_w = (const float*)d_in[9];
    const float* aw_b = (const float*)d_in[10];
    const float* vp_w = (const float*)d_in[11];
    const float* vp_b = (const float*)d_in[12];
    const float* op_w = (const float*)d_in[13];
    const float* op_b = (const float*)d_in[14];
    const float* ln1g = (const float*)d_in[15];
    const float* ln1b = (const float*)d_in[16];
    const float* ipw  = (const float*)d_in[17];
    const float* ipb  = (const float*)d_in[18];
    const float* mow  = (const float*)d_in[19];
    const float* mob  = (const float*)d_in[20];
    const float* ln3g = (const float*)d_in[21];
    const float* ln3b = (const float*)d_in[22];
    const float* l1w  = (const float*)d_in[23];
    const float* l1b  = (const float*)d_in[24];
    const float* l2w  = (const float*)d_in[25];
    const float* l2b  = (const float*)d_in[26];
    const float* ln2g = (const float*)d_in[27];
    const float* ln2b = (const float*)d_in[28];

    float* ws = (float*)d_ws;
    float*          oa     = ws;
    unsigned short* srcb   = (unsigned short*)(ws + SFL + SFL / 2);
    unsigned short* mscb   = srcb;
    unsigned short* qbf    = (unsigned short*)(ws + 2 * SFL);
    unsigned short* valb   = (unsigned short*)(ws + 2 * SFL + SFL / 2);
    float*          gen32  = ws + 3 * SFL;
    float*          x12    = ws + 4 * SFL;
    unsigned short* wb     = (unsigned short*)(ws + 5 * SFL);
    unsigned short* hidden = (unsigned short*)ws;   // N x 1024 bf16 overlays [0,2.0)

    unsigned short* wb_vp = wb;
    unsigned short* wb_so = wb + 65536;             // so(256 rows) then aw(128 rows)
    unsigned short* wb_aw = wb + 131072;
    unsigned short* wb_op = wb + 163840;
    unsigned short* wb_wq = wb + 229376;
    unsigned short* wb_mo = wb + 294912;
    unsigned short* wb_l1 = wb + 360448;
    unsigned short* wb_l2 = wb + 622592;            // end 884736 shorts
    float* kvk  = ws + 5 * SFL + 442368;
    float* kvv  = kvk + (size_t)BB * LT * D;
    float* sobc = kvv + (size_t)BB * LT * D;

    const int M = NROWS;
    const int gx   = (M + 127) / 128;               // 316
    const int gx64 = (M + 63) / 64;                 // 632
    const dim3 blk(256);
    const int n4 = (int)(SFL / 4);
    const int vgrid = (n4 + 255) / 256;
    const int dgrid = (M + 7) / 8;
    const int lgrid = (M + 3) / 4;

    // 0. weight casts
    W8 w8;
    w8.s[0] = vp_w; w8.d[0] = wb_vp; w8.n[0] = 65536;
    w8.s[1] = so_w; w8.d[1] = wb_so; w8.n[1] = 65536;
    w8.s[2] = aw_w; w8.d[2] = wb_aw; w8.n[2] = 32768;
    w8.s[3] = op_w; w8.d[3] = wb_op; w8.n[3] = 65536;
    w8.s[4] = ipw;  w8.d[4] = wb_wq; w8.n[4] = 65536;
    w8.s[5] = mow;  w8.d[5] = wb_mo; w8.n[5] = 65536;
    w8.s[6] = l1w;  w8.d[6] = wb_l1; w8.n[6] = 262144;
    w8.s[7] = l2w;  w8.d[7] = wb_l2; w8.n[7] = 262144;
    cast_w8<<<dim3(128, 8), blk, 0, stream>>>(w8);
    cat_bias<<<dim3(1), dim3(384), 0, stream>>>(so_b, aw_b, sobc);
    // 1. srcb = bf16(src), qbf = bf16(src+pos)
    cast_pair<<<dim3(vgrid), blk, 0, stream>>>((const float4*)src, (const float4*)pos,
                                               (ushort4*)srcb, (ushort4*)qbf, n4);
    // 2. value = src @ vp^T + b -> bf16   [64-row tiles: 1264 blocks]
    gemm_mfma64<<<dim3(gx64, 2), blk, 0, stream>>>(srcb, wb_vp, vp_b, nullptr, valb, M, 256, 256, 0);
    // 3. merged offs+logits = q @ [so;aw]^T + b -> oa fp32 (N x 384)  [1896 blocks]
    gemm_mfma64<<<dim3(gx64, 3), blk, 0, stream>>>(qbf, wb_so, sobc, oa, nullptr, M, 384, 256, 0);
    // 4. deformable sampling (softmax fused, XCD-swizzled) -> mscore bf16
    msdeform<<<dim3(dgrid), blk, 0, stream>>>(valb, oa, refp, mscb);
    // 5. ms = mscore @ op^T + b -> fp32
    gemm_mfma64<<<dim3(gx64, 2), blk, 0, stream>>>(mscb, wb_op, op_b, gen32, nullptr, M, 256, 256, 0);
    // 6. x1 = LN(src + ms) -> x12; q2 = bf16(x1 + pos) -> qbf (fused)
    add_ln<<<dim3(lgrid), blk, 0, stream>>>(src, gen32, ln1g, ln1b, pos, x12, qbf);
    // 7. text K/V + text passthrough out (fused)
    float* outx = (float*)d_out;
    text_kv<<<dim3(BB * LT), blk, 0, stream>>>(text, ipw, ipb, kvk, kvv, outx + SFL);
    // 8. qh = q2 @ wq^T + bq -> fp32
    gemm_mfma64<<<dim3(gx64, 2), blk, 0, stream>>>(qbf, wb_wq, ipb, gen32, nullptr, M, 256, 256, 0);
    // 9. ctx = attn(qh, K, V) -> bf16 (qbf reused)
    text_attn<<<dim3((LQ + 7) / 8, BB), blk, 0, stream>>>(gen32, kvk, kvv, qbf);
    // 10. mha = ctx @ mow^T + b -> fp32
    gemm_mfma64<<<dim3(gx64, 2), blk, 0, stream>>>(qbf, wb_mo, mob, gen32, nullptr, M, 256, 256, 0);
    // 11. x2 = LN(x1 + mha) -> x12 in-place; bf16 copy -> qbf
    add_ln<<<dim3(lgrid), blk, 0, stream>>>(x12, gen32, ln3g, ln3b, nullptr, x12, qbf);
    // 12. hidden = relu(x2 @ l1^T + b) -> bf16   [N=1024: grid already 2528]
    gemm_mfma<<<dim3(gx, 8), blk, 0, stream>>>(qbf, wb_l1, l1b, nullptr, hidden, M, 1024, 256, 1);
    // 13. ffn = hidden @ l2^T + b -> d_out (fp32 scratch)   [64-row tiles, K=1024]
    gemm_mfma64<<<dim3(gx64, 2), blk, 0, stream>>>(hidden, wb_l2, l2b, outx, nullptr, M, 256, 1024, 0);
    // 14. x3 = LN(x2 + ffn) -> d_out
    add_ln<<<dim3(lgrid), blk, 0, stream>>>(x12, outx, ln2g, ln2b, nullptr, outx, nullptr);
}

// Round 9
// 631.803 us; speedup vs baseline: 1.0811x; 1.0319x over previous
//
#include <hip/hip_runtime.h>
#include <math.h>

// ---------------- problem constants ----------------
#define D     256
#define NH    8
#define HDIM  32
#define NL    4
#define NPT   4
#define DFF   1024
#define BB    2
#define LT    20
#define LQ    20197
#define NROWS (BB*LQ)                 // 40394
#define SFL   ((size_t)NROWS * D)     // floats per N x 256 buffer

typedef __attribute__((ext_vector_type(8))) short bf16x8;
typedef __attribute__((ext_vector_type(4))) float f32x4;

__device__ __forceinline__ unsigned short f2b(float f) {
    unsigned int u = __float_as_uint(f);
    unsigned int r = (u + 0x7FFFu + ((u >> 16) & 1u)) >> 16;   // RNE
    return (unsigned short)r;
}
__device__ __forceinline__ float b2f(unsigned short u) {
    return __uint_as_float((unsigned int)u << 16);
}
__device__ __forceinline__ unsigned int pk2(float a, float b) {
    return (unsigned int)f2b(a) | ((unsigned int)f2b(b) << 16);
}

// DPP quad_perm helpers (compile-time control). Broadcast-from-quad-lane-L
// control word is L*0b01010101 = L*85. xor1 = 0xB1, xor2 = 0x4E.
template<int CTRL>
__device__ __forceinline__ int dppi(int v) {
    return __builtin_amdgcn_update_dpp(0, v, CTRL, 0xF, 0xF, true);
}
template<int CTRL>
__device__ __forceinline__ float dppf(float v) {
    return __uint_as_float((unsigned int)__builtin_amdgcn_update_dpp(
        0, (int)__float_as_uint(v), CTRL, 0xF, 0xF, true));
}

#define GLDS16(g, l) __builtin_amdgcn_global_load_lds( \
    (const __attribute__((address_space(1))) unsigned int*)(g), \
    (__attribute__((address_space(3))) unsigned int*)(l), 16, 0, 0)

// =====================================================================
// bf16 MFMA GEMM (128x128 tile): used only where grid is already large
// (step 12: N=1024 -> 2528 blocks). 4 waves (2x2 of 64x64), dbuf.
// =====================================================================
__global__ __launch_bounds__(256) void gemm_mfma(const unsigned short* __restrict__ A,
                                                 const unsigned short* __restrict__ W,
                                                 const float* __restrict__ bias,
                                                 float* __restrict__ Cf,
                                                 unsigned short* __restrict__ Cb,
                                                 int M, int Nout, int K, int relu)
{
    __shared__ __align__(16) unsigned short As[2][128 * 32];   // 2 x 8 KB
    __shared__ __align__(16) unsigned short Ws[2][128 * 32];   // 2 x 8 KB
    const int tid  = threadIdx.x;
    const int wave = tid >> 6, lane = tid & 63;
    const int row0 = blockIdx.x * 128, n0 = blockIdx.y * 128;
    const int wm = (wave >> 1) * 64, wn = (wave & 1) * 64;

    const int srow = (wave << 5) + (lane >> 2);
    const int kcol = (lane & 3) << 3;
    const int ar0 = min(row0 + srow,      M - 1);
    const int ar1 = min(row0 + srow + 16, M - 1);
    const unsigned short* Ap0 = A + (size_t)ar0 * K + kcol;
    const unsigned short* Ap1 = A + (size_t)ar1 * K + kcol;
    const unsigned short* Wp0 = W + (size_t)(n0 + srow) * K + kcol;
    const unsigned short* Wp1 = W + (size_t)(n0 + srow + 16) * K + kcol;
    const int aoff0 = (wave << 10);          // per-wave staging offset (shorts)
    const int aoff1 = (wave << 10) + 512;

    f32x4 acc[4][4];
#pragma unroll
    for (int i = 0; i < 4; ++i)
#pragma unroll
        for (int j = 0; j < 4; ++j)
#pragma unroll
            for (int r = 0; r < 4; ++r) acc[i][j][r] = 0.f;

    const int fr = lane & 15;
    const int fk = (lane >> 4) << 3;

    // prologue: stage tile 0 into buffer 0
    GLDS16(Ap0, &As[0][aoff0]);
    GLDS16(Ap1, &As[0][aoff1]);
    GLDS16(Wp0, &Ws[0][aoff0]);
    GLDS16(Wp1, &Ws[0][aoff1]);
    __syncthreads();

    const int nt = K >> 5;
    int cur = 0;
    for (int t = 0; t < nt; ++t) {
        if (t + 1 < nt) {
            const int k1 = (t + 1) << 5;
            GLDS16(Ap0 + k1, &As[cur ^ 1][aoff0]);
            GLDS16(Ap1 + k1, &As[cur ^ 1][aoff1]);
            GLDS16(Wp0 + k1, &Ws[cur ^ 1][aoff0]);
            GLDS16(Wp1 + k1, &Ws[cur ^ 1][aoff1]);
        }
        bf16x8 af[4], wf[4];
#pragma unroll
        for (int t4 = 0; t4 < 4; ++t4) {
            af[t4] = *(const bf16x8*)&As[cur][(wm + t4 * 16 + fr) * 32 + fk];
            wf[t4] = *(const bf16x8*)&Ws[cur][(wn + t4 * 16 + fr) * 32 + fk];
        }
#pragma unroll
        for (int i = 0; i < 4; ++i)
#pragma unroll
            for (int j = 0; j < 4; ++j)
                acc[i][j] = __builtin_amdgcn_mfma_f32_16x16x32_bf16(af[i], wf[j], acc[i][j], 0, 0, 0);
        __syncthreads();
        cur ^= 1;
    }

    const int rq = (lane >> 4) << 2;
    const int cq = lane & 15;
#pragma unroll
    for (int mt = 0; mt < 4; ++mt) {
#pragma unroll
        for (int r = 0; r < 4; ++r) {
            const int row = row0 + wm + mt * 16 + rq + r;
            if (row < M) {
#pragma unroll
                for (int nt2 = 0; nt2 < 4; ++nt2) {
                    const int c = n0 + wn + nt2 * 16 + cq;
                    float v = acc[mt][nt2][r] + bias[c];
                    if (relu) v = fmaxf(v, 0.f);
                    if (Cb) Cb[(size_t)row * Nout + c] = f2b(v);
                    else    Cf[(size_t)row * Nout + c] = v;
                }
            }
        }
    }
}

// =====================================================================
// bf16 MFMA GEMM 64x128-tile body (r5's proven form: BK=32, 12 KB LDS).
// Shared by gemm_mfma64 and the merged gemm_dual launch.
// =====================================================================
__device__ __forceinline__ void gemm64_body(const unsigned short* __restrict__ A,
                                            const unsigned short* __restrict__ W,
                                            const float* __restrict__ bias,
                                            float* __restrict__ Cf,
                                            unsigned short* __restrict__ Cb,
                                            int M, int Nout, int K, int relu,
                                            int row0, int n0)
{
    __shared__ __align__(16) unsigned short As[64 * 32];     // 4 KB
    __shared__ __align__(16) unsigned short Ws[128 * 32];    // 8 KB
    const int tid  = threadIdx.x;
    const int wave = tid >> 6, lane = tid & 63;
    const int wn = wave << 5;                 // col offset 0/32/64/96

    // staging: wave v stages A rows [16v,16v+16) and W rows [32v,32v+32)
    const int srow = lane >> 2;
    const int kcol = (lane & 3) << 3;
    const int arow = min(row0 + (wave << 4) + srow, M - 1);
    const unsigned short* Ap  = A + (size_t)arow * K + kcol;
    const unsigned short* Wp0 = W + (size_t)(n0 + (wave << 5) + srow) * K + kcol;
    const unsigned short* Wp1 = W + (size_t)(n0 + (wave << 5) + 16 + srow) * K + kcol;
    unsigned short* lA  = &As[wave << 9];     // 16 rows * 32 = 512 shorts/wave
    unsigned short* lW0 = &Ws[wave << 10];    // 32 rows * 32 = 1024 shorts/wave
    unsigned short* lW1 = &Ws[(wave << 10) + 512];

    f32x4 acc[4][2];
#pragma unroll
    for (int i = 0; i < 4; ++i)
#pragma unroll
        for (int j = 0; j < 2; ++j)
#pragma unroll
            for (int r = 0; r < 4; ++r) acc[i][j][r] = 0.f;

    const int fr = lane & 15;
    const int fk = (lane >> 4) << 3;

    for (int k0 = 0; k0 < K; k0 += 32) {
        GLDS16(Ap + k0, lA);
        GLDS16(Wp0 + k0, lW0);
        GLDS16(Wp1 + k0, lW1);
        __syncthreads();
        bf16x8 af[4], wf[2];
#pragma unroll
        for (int i = 0; i < 4; ++i)
            af[i] = *(const bf16x8*)&As[(i * 16 + fr) * 32 + fk];
#pragma unroll
        for (int j = 0; j < 2; ++j)
            wf[j] = *(const bf16x8*)&Ws[(wn + j * 16 + fr) * 32 + fk];
#pragma unroll
        for (int i = 0; i < 4; ++i)
#pragma unroll
            for (int j = 0; j < 2; ++j)
                acc[i][j] = __builtin_amdgcn_mfma_f32_16x16x32_bf16(af[i], wf[j], acc[i][j], 0, 0, 0);
        __syncthreads();
    }

    const int rq = (lane >> 4) << 2;
    const int cq = lane & 15;
#pragma unroll
    for (int i = 0; i < 4; ++i) {
#pragma unroll
        for (int r = 0; r < 4; ++r) {
            const int row = row0 + i * 16 + rq + r;
            if (row < M) {
#pragma unroll
                for (int j = 0; j < 2; ++j) {
                    const int c = n0 + wn + j * 16 + cq;
                    float v = acc[i][j][r] + bias[c];
                    if (relu) v = fmaxf(v, 0.f);
                    if (Cb) Cb[(size_t)row * Nout + c] = f2b(v);
                    else    Cf[(size_t)row * Nout + c] = v;
                }
            }
        }
    }
}

__global__ __launch_bounds__(256) void gemm_mfma64(const unsigned short* __restrict__ A,
                                                   const unsigned short* __restrict__ W,
                                                   const float* __restrict__ bias,
                                                   float* __restrict__ Cf,
                                                   unsigned short* __restrict__ Cb,
                                                   int M, int Nout, int K, int relu)
{
    gemm64_body(A, W, bias, Cf, Cb, M, Nout, K, relu, blockIdx.x * 64, blockIdx.y * 128);
}

// Merged launch for pipeline steps 2+3 (independent thin GEMMs, K=256):
// blockIdx.y 0..1 -> job0 (value proj, Nout=256, bf16 out)
// blockIdx.y 2..4 -> job1 (offs+logits, Nout=384, fp32 out)
__global__ __launch_bounds__(256) void gemm_dual(const unsigned short* __restrict__ A0,
                                                 const unsigned short* __restrict__ W0,
                                                 const float* __restrict__ b0,
                                                 unsigned short* __restrict__ Cb0,
                                                 const unsigned short* __restrict__ A1,
                                                 const unsigned short* __restrict__ W1,
                                                 const float* __restrict__ b1,
                                                 float* __restrict__ Cf1,
                                                 int M)
{
    const int y = blockIdx.y;
    if (y < 2)
        gemm64_body(A0, W0, b0, nullptr, Cb0, M, 256, 256, 0, blockIdx.x * 64, y * 128);
    else
        gemm64_body(A1, W1, b1, Cf1, nullptr, M, 384, 256, 0, blockIdx.x * 64, (y - 2) * 128);
}

// ---------------------------------------------------------------------
// merged prep kernel: cast_pair (all blocks) + 8-segment weight cast
// (blocks 0..127, strided) + bias concat (block 200). Replaces three
// launches (cast_w8, cat_bias, cast_pair) with one.
// ---------------------------------------------------------------------
struct W8 {
    const float* s[8];
    unsigned short* d[8];
    int n[8];
};
struct PrepArgs {
    W8 w8;
    const float* so_b; const float* aw_b; float* sobc;
    const float4* src; const float4* pos;
    ushort4* srcb; ushort4* qbf; int n4;
};
__global__ __launch_bounds__(256) void prep(PrepArgs p)
{
    const int bid = blockIdx.x, tid = threadIdx.x;
    // cast_pair portion
    const int i = bid * 256 + tid;
    if (i < p.n4) {
        const float4 s = p.src[i], q = p.pos[i];
        p.srcb[i] = make_ushort4(f2b(s.x), f2b(s.y), f2b(s.z), f2b(s.w));
        p.qbf[i]  = make_ushort4(f2b(s.x + q.x), f2b(s.y + q.y), f2b(s.z + q.z), f2b(s.w + q.w));
    }
    // weight casts: blocks 0..127 stride across all 8 segments
    if (bid < 128) {
#pragma unroll
        for (int seg = 0; seg < 8; ++seg) {
            const float* s = p.w8.s[seg];
            unsigned short* d = p.w8.d[seg];
            const int n = p.w8.n[seg];
            for (int k = bid * 256 + tid; k < n; k += 128 * 256)
                d[k] = f2b(s[k]);
        }
    }
    // bias concat (384 elems)
    if (bid == 200) {
        for (int t = tid; t < 384; t += 256)
            p.sobc[t] = (t < 256) ? p.so_b[t] : p.aw_b[t - 256];
    }
}

// ---------------------------------------------------------------------
// multi-scale deformable sampling (r8 form, unchanged: distributed coord
// math + level-major gather + bijective XCD swizzle; ~90.6 us, 150 MB
// fetch; cache-BW-bound at ~14.5 TB/s effective gather rate).
// ---------------------------------------------------------------------
#define SEL4(a0,a1,a2,a3) (j < 2 ? (j == 0 ? (a0) : (a1)) : (j == 2 ? (a2) : (a3)))

__global__ __launch_bounds__(256) void msdeform(const unsigned short* __restrict__ value,
                                                const float* __restrict__ oa,
                                                const float* __restrict__ refp,
                                                unsigned short* __restrict__ out)
{
    // bijective XCD swizzle: xcd = orig%8 gets chunk of q(+1) consecutive ids
    const int nwg  = gridDim.x;
    const int orig = blockIdx.x;
    const int xcd  = orig & 7;
    const int qch  = nwg >> 3, rch = nwg & 7;
    const int bid  = (xcd < rch ? xcd * (qch + 1) : rch * (qch + 1) + (xcd - rch) * qch)
                   + (orig >> 3);

    const int tid  = threadIdx.x;
    const int lane = tid & 63;
    const int row  = bid * 8 + ((tid >> 6) << 1) + (lane >> 5);
    if (row >= NROWS) return;
    const int b   = row / LQ;
    const int sub = lane & 31;
    const int h   = sub >> 2;
    const int j   = sub & 3;                 // this lane's level AND channel-chunk
    const int ch  = (h << 5) + (j << 3);
    const unsigned short* vbase = value + (size_t)b * LQ * D + ch;

    const float* orow = oa + (size_t)row * 384;
    const float4 o0 = *(const float4*)(orow + (h << 5) + (j << 3));
    const float4 o1 = *(const float4*)(orow + (h << 5) + (j << 3) + 4);
    const float oxr[4] = {o0.x, o0.z, o1.x, o1.z};
    const float oyr[4] = {o0.y, o0.w, o1.y, o1.w};
    const float4 lg = *(const float4*)(orow + 256 + (h << 4) + (j << 2));
    float mx = fmaxf(fmaxf(lg.x, lg.y), fmaxf(lg.z, lg.w));
    mx = fmaxf(mx, dppf<0xB1>(mx));
    mx = fmaxf(mx, dppf<0x4E>(mx));
    const float e0 = __expf(lg.x - mx), e1 = __expf(lg.y - mx);
    const float e2 = __expf(lg.z - mx), e3 = __expf(lg.w - mx);
    float sm = e0 + e1 + e2 + e3;
    sm += dppf<0xB1>(sm);
    sm += dppf<0x4E>(sm);
    const float inv = 1.f / sm;
    const float pr[4] = {e0 * inv, e1 * inv, e2 * inv, e3 * inv};

    const int   Wi   = SEL4(152, 76, 38, 19);
    const int   Hi   = SEL4(100, 50, 25, 13);
    const int   st   = SEL4(0, 15200, 19000, 19950);
    const float invW = SEL4(1.f/152.f, 1.f/76.f, 1.f/38.f, 1.f/19.f);
    const float invH = SEL4(1.f/100.f, 1.f/50.f, 1.f/25.f, 1.f/13.f);
    const float Wf = (float)Wi, Hf = (float)Hi;
    const float2 rxy = *(const float2*)(refp + (size_t)row * 8 + (j << 1));

    unsigned int ip[8];
    float wcs[16];
#pragma unroll
    for (int p = 0; p < 4; ++p) {
        const float x = fmaf(oxr[p], invW, rxy.x) * Wf - 0.5f;
        const float y = fmaf(oyr[p], invH, rxy.y) * Hf - 0.5f;
        const float x0f = floorf(x), y0f = floorf(y);
        const float lx = x - x0f, ly = y - y0f;
        const int x0 = (int)x0f, y0 = (int)y0f;
        const int x1 = x0 + 1,  y1 = y0 + 1;
        const float vx0 = (x0 >= 0 && x0 < Wi) ? 1.f : 0.f;
        const float vx1 = (x1 >= 0 && x1 < Wi) ? 1.f : 0.f;
        const float vy0 = (y0 >= 0 && y0 < Hi) ? 1.f : 0.f;
        const float vy1 = (y1 >= 0 && y1 < Hi) ? 1.f : 0.f;
        const int cx0 = min(max(x0, 0), Wi - 1), cx1 = min(max(x1, 0), Wi - 1);
        const int cy0 = min(max(y0, 0), Hi - 1), cy1 = min(max(y1, 0), Hi - 1);
        const float wap = pr[p];
        const float wx0 = (1.f - lx) * vx0,        wx1 = lx * vx1;
        const float wy0 = (1.f - ly) * vy0 * wap,  wy1 = ly * vy1 * wap;
        const int r0 = st + cy0 * Wi, r1 = st + cy1 * Wi;
        ip[2*p]     = (unsigned int)(r0 + cx0) | ((unsigned int)(r0 + cx1) << 16);
        ip[2*p + 1] = (unsigned int)(r1 + cx0) | ((unsigned int)(r1 + cx1) << 16);
        wcs[4*p]     = wx0 * wy0;
        wcs[4*p + 1] = wx1 * wy0;
        wcs[4*p + 2] = wx0 * wy1;
        wcs[4*p + 3] = wx1 * wy1;
    }

    float acc[8] = {0.f,0.f,0.f,0.f,0.f,0.f,0.f,0.f};

#define GATHER(i_, w_) do { \
        const uint4 g_ = *(const uint4*)(vbase + ((size_t)(i_) << 8)); \
        acc[0] = fmaf(w_, __uint_as_float(g_.x << 16),          acc[0]); \
        acc[1] = fmaf(w_, __uint_as_float(g_.x & 0xffff0000u),  acc[1]); \
        acc[2] = fmaf(w_, __uint_as_float(g_.y << 16),          acc[2]); \
        acc[3] = fmaf(w_, __uint_as_float(g_.y & 0xffff0000u),  acc[3]); \
        acc[4] = fmaf(w_, __uint_as_float(g_.z << 16),          acc[4]); \
        acc[5] = fmaf(w_, __uint_as_float(g_.z & 0xffff0000u),  acc[5]); \
        acc[6] = fmaf(w_, __uint_as_float(g_.w << 16),          acc[6]); \
        acc[7] = fmaf(w_, __uint_as_float(g_.w & 0xffff0000u),  acc[7]); \
    } while (0)

#define POINT(L, p) do { \
        const unsigned int pk0_ = (unsigned int)dppi<(L)*85>((int)ip[2*(p)]); \
        const unsigned int pk1_ = (unsigned int)dppi<(L)*85>((int)ip[2*(p)+1]); \
        const float cw0_ = dppf<(L)*85>(wcs[4*(p)]); \
        const float cw1_ = dppf<(L)*85>(wcs[4*(p)+1]); \
        const float cw2_ = dppf<(L)*85>(wcs[4*(p)+2]); \
        const float cw3_ = dppf<(L)*85>(wcs[4*(p)+3]); \
        GATHER(pk0_ & 0xffffu, cw0_); \
        GATHER(pk0_ >> 16,     cw1_); \
        GATHER(pk1_ & 0xffffu, cw2_); \
        GATHER(pk1_ >> 16,     cw3_); \
    } while (0)

#define LEVEL(L) do { POINT(L,0); POINT(L,1); POINT(L,2); POINT(L,3); } while (0)

    LEVEL(0); LEVEL(1); LEVEL(2); LEVEL(3);

#undef LEVEL
#undef POINT
#undef GATHER

    uint4 o;
    o.x = pk2(acc[0], acc[1]); o.y = pk2(acc[2], acc[3]);
    o.z = pk2(acc[4], acc[5]); o.w = pk2(acc[6], acc[7]);
    *(uint4*)(out + (size_t)row * D + ch) = o;
}

// ---------------------------------------------------------------------
// out = LayerNorm(a + b) * g + beta over D=256. ONE WAVE per row.
// ---------------------------------------------------------------------
__global__ __launch_bounds__(256) void add_ln(const float* a, const float* b,
                                              const float* __restrict__ g,
                                              const float* __restrict__ be,
                                              const float* __restrict__ pos,
                                              float* out, unsigned short* outb)
{
    const int lane = threadIdx.x & 63;
    const int row  = blockIdx.x * 4 + (threadIdx.x >> 6);
    if (row >= NROWS) return;
    const size_t base = (size_t)row * D + (lane << 2);
    const float4 av = *(const float4*)(a + base);
    const float4 bv = *(const float4*)(b + base);
    float4 v = make_float4(av.x + bv.x, av.y + bv.y, av.z + bv.z, av.w + bv.w);
    float s = v.x + v.y + v.z + v.w;
#pragma unroll
    for (int off = 1; off < 64; off <<= 1) s += __shfl_xor(s, off);
    const float mean = s * (1.f / 256.f);
    const float4 d = make_float4(v.x - mean, v.y - mean, v.z - mean, v.w - mean);
    float q = d.x*d.x + d.y*d.y + d.z*d.z + d.w*d.w;
#pragma unroll
    for (int off = 1; off < 64; off <<= 1) q += __shfl_xor(q, off);
    const float rstd = rsqrtf(q * (1.f / 256.f) + 1e-5f);
    const float4 gv = *(const float4*)(g  + (lane << 2));
    const float4 bev = *(const float4*)(be + (lane << 2));
    float4 o;
    o.x = d.x * rstd * gv.x + bev.x;
    o.y = d.y * rstd * gv.y + bev.y;
    o.z = d.z * rstd * gv.z + bev.z;
    o.w = d.w * rstd * gv.w + bev.w;
    *(float4*)(out + base) = o;
    if (outb) {
        float4 p = make_float4(0.f, 0.f, 0.f, 0.f);
        if (pos) p = *(const float4*)(pos + base);
        uint2 u;
        u.x = pk2(o.x + p.x, o.y + p.y);
        u.y = pk2(o.z + p.z, o.w + p.w);
        *(uint2*)(outb + base) = u;
    }
}

// ---------------------------------------------------------------------
// text K/V projections + text passthrough output (fused).
// ---------------------------------------------------------------------
__global__ __launch_bounds__(256) void text_kv(const float* __restrict__ text,
                                               const float* __restrict__ ipw,
                                               const float* __restrict__ ipb,
                                               float* __restrict__ kh,
                                               float* __restrict__ vh,
                                               float* __restrict__ outtxt)
{
    __shared__ float ts[D];
    const int row = blockIdx.x, t = threadIdx.x;
    const float tv = text[(size_t)row * D + t];
    ts[t] = tv;
    outtxt[(size_t)row * D + t] = tv;
    __syncthreads();
    const float* wk = ipw + (size_t)(D + t) * D;
    const float* wv = ipw + (size_t)(2 * D + t) * D;
    float sk = ipb[D + t], sv = ipb[2 * D + t];
    for (int k = 0; k < D; ++k) {
        sk = fmaf(ts[k], wk[k], sk);
        sv = fmaf(ts[k], wv[k], sv);
    }
    kh[(size_t)row * D + t] = sk;
    vh[(size_t)row * D + t] = sv;
}

// ---------------------------------------------------------------------
// cross-attention to text: 8 query rows per block; V + 8 q-rows staged in
// LDS once; K-fragment and V-column hoisted to registers and reused.
// grid: (ceil(LQ/8), B)
// ---------------------------------------------------------------------
__global__ __launch_bounds__(256) void text_attn(const float* __restrict__ qh,
                                                 const float* __restrict__ kh,
                                                 const float* __restrict__ vh,
                                                 unsigned short* __restrict__ ctx)
{
    __shared__ float vs[LT * D];      // 20 KB
    __shared__ float qs[8][D];        // 8 KB
    const int b  = blockIdx.y;
    const int q0 = blockIdx.x * 8;
    const int t  = threadIdx.x;
    const int nr = min(8, LQ - q0);

    {
        const float4* vsrc = (const float4*)(vh + (size_t)b * LT * D);
        float4* vdst = (float4*)vs;
#pragma unroll
        for (int i = 0; i < 5; ++i) vdst[t + 256 * i] = vsrc[t + 256 * i];
        for (int r = 0; r < nr; ++r)
            qs[r][t] = qh[((size_t)b * LQ + q0 + r) * D + t];
    }
    __syncthreads();

    const int h = t >> 5, d = t & 31;
    const int lane = t & 63;
    float kf[32];
    if (d < LT) {
        const float4* kr = (const float4*)(kh + (size_t)(b * LT + d) * D + h * HDIM);
#pragma unroll
        for (int i = 0; i < 8; ++i) {
            const float4 kv = kr[i];
            kf[4*i] = kv.x; kf[4*i+1] = kv.y; kf[4*i+2] = kv.z; kf[4*i+3] = kv.w;
        }
    }
    float vv[LT];
#pragma unroll
    for (int k = 0; k < LT; ++k) vv[k] = vs[k * D + t];

    for (int r = 0; r < nr; ++r) {
        float sc = -1e30f;
        if (d < LT) {
            const float4* qq = (const float4*)(qs[r] + h * HDIM);
            float s = 0.f;
#pragma unroll
            for (int i = 0; i < 8; ++i) {
                const float4 qv = qq[i];
                s = fmaf(qv.x, kf[4*i],   s); s = fmaf(qv.y, kf[4*i+1], s);
                s = fmaf(qv.z, kf[4*i+2], s); s = fmaf(qv.w, kf[4*i+3], s);
            }
            sc = s * 0.17677669529663687f;   // 1/sqrt(32)
        }
        float mx = sc;
#pragma unroll
        for (int off = 1; off < 32; off <<= 1) mx = fmaxf(mx, __shfl_xor(mx, off));
        const float e = (d < LT) ? __expf(sc - mx) : 0.f;
        float sm = e;
#pragma unroll
        for (int off = 1; off < 32; off <<= 1) sm += __shfl_xor(sm, off);
        const float pr = e * (1.f / sm);
        float o0 = 0.f, o1 = 0.f;
#pragma unroll
        for (int k = 0; k < LT; k += 2) {
            const float p0 = __shfl(pr, (lane & 32) | k);
            const float p1 = __shfl(pr, (lane & 32) | (k + 1));
            o0 = fmaf(p0, vv[k],     o0);
            o1 = fmaf(p1, vv[k + 1], o1);
        }
        ctx[((size_t)b * LQ + q0 + r) * D + t] = f2b(o0 + o1);
    }
}

// =====================================================================
extern "C" void kernel_launch(void* const* d_in, const int* in_sizes, int n_in,
                              void* d_out, int out_size, void* d_ws, size_t ws_size,
                              hipStream_t stream)
{
    const float* src  = (const float*)d_in[0];
    const float* pos  = (const float*)d_in[1];
    const float* refp = (const float*)d_in[2];
    const float* text = (const float*)d_in[5];
    const float* so_w = (const float*)d_in[7];
    const float* so_b = (const float*)d_in[8];
    const float* aw_w = (const float*)d_in[9];
    const float* aw_b = (const float*)d_in[10];
    const float* vp_w = (const float*)d_in[11];
    const float* vp_b = (const float*)d_in[12];
    const float* op_w = (const float*)d_in[13];
    const float* op_b = (const float*)d_in[14];
    const float* ln1g = (const float*)d_in[15];
    const float* ln1b = (const float*)d_in[16];
    const float* ipw  = (const float*)d_in[17];
    const float* ipb  = (const float*)d_in[18];
    const float* mow  = (const float*)d_in[19];
    const float* mob  = (const float*)d_in[20];
    const float* ln3g = (const float*)d_in[21];
    const float* ln3b = (const float*)d_in[22];
    const float* l1w  = (const float*)d_in[23];
    const float* l1b  = (const float*)d_in[24];
    const float* l2w  = (const float*)d_in[25];
    const float* l2b  = (const float*)d_in[26];
    const float* ln2g = (const float*)d_in[27];
    const float* ln2b = (const float*)d_in[28];

    float* ws = (float*)d_ws;
    float*          oa     = ws;
    unsigned short* srcb   = (unsigned short*)(ws + SFL + SFL / 2);
    unsigned short* mscb   = srcb;
    unsigned short* qbf    = (unsigned short*)(ws + 2 * SFL);
    unsigned short* valb   = (unsigned short*)(ws + 2 * SFL + SFL / 2);
    float*          gen32  = ws + 3 * SFL;
    float*          x12    = ws + 4 * SFL;
    unsigned short* wb     = (unsigned short*)(ws + 5 * SFL);
    unsigned short* hidden = (unsigned short*)ws;   // N x 1024 bf16 overlays [0,2.0)

    unsigned short* wb_vp = wb;
    unsigned short* wb_so = wb + 65536;             // so(256 rows) then aw(128 rows)
    unsigned short* wb_aw = wb + 131072;
    unsigned short* wb_op = wb + 163840;
    unsigned short* wb_wq = wb + 229376;
    unsigned short* wb_mo = wb + 294912;
    unsigned short* wb_l1 = wb + 360448;
    unsigned short* wb_l2 = wb + 622592;            // end 884736 shorts
    float* kvk  = ws + 5 * SFL + 442368;
    float* kvv  = kvk + (size_t)BB * LT * D;
    float* sobc = kvv + (size_t)BB * LT * D;

    const int M = NROWS;
    const int gx   = (M + 127) / 128;               // 316
    const int gx64 = (M + 63) / 64;                 // 632
    const dim3 blk(256);
    const int n4 = (int)(SFL / 4);
    const int vgrid = (n4 + 255) / 256;
    const int dgrid = (M + 7) / 8;
    const int lgrid = (M + 3) / 4;

    // 0+1. merged prep: weight casts + bias concat + srcb/qbf casts  [1 launch]
    PrepArgs pa;
    pa.w8.s[0] = vp_w; pa.w8.d[0] = wb_vp; pa.w8.n[0] = 65536;
    pa.w8.s[1] = so_w; pa.w8.d[1] = wb_so; pa.w8.n[1] = 65536;
    pa.w8.s[2] = aw_w; pa.w8.d[2] = wb_aw; pa.w8.n[2] = 32768;
    pa.w8.s[3] = op_w; pa.w8.d[3] = wb_op; pa.w8.n[3] = 65536;
    pa.w8.s[4] = ipw;  pa.w8.d[4] = wb_wq; pa.w8.n[4] = 65536;
    pa.w8.s[5] = mow;  pa.w8.d[5] = wb_mo; pa.w8.n[5] = 65536;
    pa.w8.s[6] = l1w;  pa.w8.d[6] = wb_l1; pa.w8.n[6] = 262144;
    pa.w8.s[7] = l2w;  pa.w8.d[7] = wb_l2; pa.w8.n[7] = 262144;
    pa.so_b = so_b; pa.aw_b = aw_b; pa.sobc = sobc;
    pa.src = (const float4*)src; pa.pos = (const float4*)pos;
    pa.srcb = (ushort4*)srcb; pa.qbf = (ushort4*)qbf; pa.n4 = n4;
    prep<<<dim3(vgrid), blk, 0, stream>>>(pa);
    // 2+3. value proj & offs/logits in ONE launch (independent GEMMs)
    gemm_dual<<<dim3(gx64, 5), blk, 0, stream>>>(srcb, wb_vp, vp_b, valb,
                                                 qbf, wb_so, sobc, oa, M);
    // 4. deformable sampling (softmax fused, XCD-swizzled) -> mscore bf16
    msdeform<<<dim3(dgrid), blk, 0, stream>>>(valb, oa, refp, mscb);
    // 5. ms = mscore @ op^T + b -> fp32
    gemm_mfma64<<<dim3(gx64, 2), blk, 0, stream>>>(mscb, wb_op, op_b, gen32, nullptr, M, 256, 256, 0);
    // 6. x1 = LN(src + ms) -> x12; q2 = bf16(x1 + pos) -> qbf (fused)
    add_ln<<<dim3(lgrid), blk, 0, stream>>>(src, gen32, ln1g, ln1b, pos, x12, qbf);
    // 7. text K/V + text passthrough out (fused)
    float* outx = (float*)d_out;
    text_kv<<<dim3(BB * LT), blk, 0, stream>>>(text, ipw, ipb, kvk, kvv, outx + SFL);
    // 8. qh = q2 @ wq^T + bq -> fp32
    gemm_mfma64<<<dim3(gx64, 2), blk, 0, stream>>>(qbf, wb_wq, ipb, gen32, nullptr, M, 256, 256, 0);
    // 9. ctx = attn(qh, K, V) -> bf16 (qbf reused)
    text_attn<<<dim3((LQ + 7) / 8, BB), blk, 0, stream>>>(gen32, kvk, kvv, qbf);
    // 10. mha = ctx @ mow^T + b -> fp32
    gemm_mfma64<<<dim3(gx64, 2), blk, 0, stream>>>(qbf, wb_mo, mob, gen32, nullptr, M, 256, 256, 0);
    // 11. x2 = LN(x1 + mha) -> x12 in-place; bf16 copy -> qbf
    add_ln<<<dim3(lgrid), blk, 0, stream>>>(x12, gen32, ln3g, ln3b, nullptr, x12, qbf);
    // 12. hidden = relu(x2 @ l1^T + b) -> bf16   [N=1024: grid 2528]
    gemm_mfma<<<dim3(gx, 8), blk, 0, stream>>>(qbf, wb_l1, l1b, nullptr, hidden, M, 1024, 256, 1);
    // 13. ffn = hidden @ l2^T + b -> d_out (fp32 scratch)   [64-row tiles, K=1024]
    gemm_mfma64<<<dim3(gx64, 2), blk, 0, stream>>>(hidden, wb_l2, l2b, outx, nullptr, M, 256, 1024, 0);
    // 14. x3 = LN(x2 + ffn) -> d_out
    add_ln<<<dim3(lgrid), blk, 0, stream>>>(x12, outx, ln2g, ln2b, nullptr, outx, nullptr);
}